// Round 6
// baseline (1206.208 us; speedup 1.0000x reference)
//
#include <hip/hip_runtime.h>
#include <cstdint>
#include <cstddef>

// CP_TransformerDecoder on MI355X — round 6: split-K for the N=1024 GEMMs.
// Round-5 counters: fc2 M_RESID = 73us @ 5.4% occupancy (128 WGs on 256 CUs),
// 748 GB/s, MfmaUtil 8.7% -> HBM-parallelism-bound. Split K into slices
// (fc2: 4x1024, proj: 2x512) and combine via f32 atomicAdd into the residual
// stream (bias added by slice z==0 only). Everything else unchanged.

typedef __bf16 bf16_t;
typedef __bf16 bf16x8 __attribute__((ext_vector_type(8)));
typedef float  f32x4  __attribute__((ext_vector_type(4)));

#define DEVI __device__ __forceinline__

DEVI f32x4 mfma16(bf16x8 a, bf16x8 b, f32x4 c) {
  return __builtin_amdgcn_mfma_f32_16x16x32_bf16(a, b, c, 0, 0, 0);
}

DEVI void async16(const void* g, void* l) {
  __builtin_amdgcn_global_load_lds((const __attribute__((address_space(1))) void*)g,
                                   (__attribute__((address_space(3))) void*)l, 16, 0, 0);
}

DEVI float gelu_f(float v) { return 0.5f * v * (1.0f + erff(v * 0.70710678118654752440f)); }

// ---------------- preprocessing ----------------

// u_wT[c][r] = u_w[r][c]  (bf16), LDS-tiled transpose
__global__ __launch_bounds__(256) void utrans_kernel(const float* __restrict__ u_w,
                                                     bf16_t* __restrict__ out) {
  __shared__ float T[64][65];
  int t = threadIdx.x, c0 = blockIdx.x * 64;
#pragma unroll
  for (int i = 0; i < 16; ++i) {
    int idx = i * 256 + t;
    int r = idx >> 6, c = idx & 63;
    T[r][c] = u_w[r * 1024 + c0 + c];
  }
  __syncthreads();
#pragma unroll
  for (int i = 0; i < 16; ++i) {
    int idx = i * 256 + t;
    int c = idx >> 6, r = idx & 63;
    out[(size_t)(c0 + c) * 64 + r] = (bf16_t)T[r][c];
  }
}

// CPcat[l][r1][r2][f], f=0..3 from cp_att, f=4..11 from mlp_cp
__global__ __launch_bounds__(256) void cpcat_kernel(const float* __restrict__ cp_c,
    const float* __restrict__ cp_att, const float* __restrict__ mlp_cp, float* __restrict__ cpcat) {
  int idx = blockIdx.x * 256 + threadIdx.x;  // 16384 = L*64*64
  int lay = idx >> 12, ab = idx & 4095;
  const float* crow = cp_c + (size_t)ab * 64;
  float acc[12];
#pragma unroll
  for (int f = 0; f < 12; ++f) acc[f] = 0.f;
  for (int r = 0; r < 64; ++r) {
    float cv = crow[r];
    const float* wa = cp_att + lay * 256 + r * 4;
    const float* wm = mlp_cp + lay * 512 + r * 8;
#pragma unroll
    for (int f = 0; f < 4; ++f) acc[f] += cv * wa[f];
#pragma unroll
    for (int f = 0; f < 8; ++f) acc[4 + f] += cv * wm[f];
  }
  float* o = cpcat + (size_t)idx * 12;
#pragma unroll
  for (int f = 0; f < 12; ++f) o[f] = acc[f];
}

// wpatt[l][f][cout][r1] = sum_r2 CPcat[l][r1][r2][f] * v_w[cout][r2]
__global__ __launch_bounds__(256) void wp_att_kernel(const float* __restrict__ cpcat,
    const float* __restrict__ v_w, bf16_t* __restrict__ out) {
  __shared__ float ST[64][65];
  int lay = blockIdx.y;
  int f = blockIdx.x >> 3, cc = blockIdx.x & 7;
  int t = threadIdx.x;
#pragma unroll
  for (int i = 0; i < 16; ++i) {
    int idx = i * 256 + t;
    int r1 = idx >> 6, r2 = idx & 63;
    ST[r2][r1] = cpcat[(size_t)(lay * 4096 + r1 * 64 + r2) * 12 + f];
  }
  __syncthreads();
  int lane = t & 63, grp = t >> 6;
  for (int ii = 0; ii < 32; ii += 4) {
    int cb = cc * 128 + grp * 32 + ii;
    const float* v0 = v_w + (size_t)cb * 64;
    const float* v1 = v0 + 64;
    const float* v2 = v0 + 128;
    const float* v3 = v0 + 192;
    float a0 = 0.f, a1 = 0.f, a2 = 0.f, a3 = 0.f;
#pragma unroll 8
    for (int r2 = 0; r2 < 64; ++r2) {
      float sv = ST[r2][lane];
      a0 += sv * v0[r2]; a1 += sv * v1[r2]; a2 += sv * v2[r2]; a3 += sv * v3[r2];
    }
    size_t ob = ((size_t)(lay * 4 + f) * 1024 + cb) * 64 + lane;
    out[ob] = (bf16_t)a0; out[ob + 64] = (bf16_t)a1;
    out[ob + 128] = (bf16_t)a2; out[ob + 192] = (bf16_t)a3;
  }
}

// wpfc1[l][g*1024+cout][r1] = sum_rr CPcat[l][r1][g*16+(rr>>2)][4+(rr&3)] * v_w[cout][rr]
__global__ __launch_bounds__(256) void wp_fc1_kernel(const float* __restrict__ cpcat,
    const float* __restrict__ v_w, bf16_t* __restrict__ out) {
  __shared__ float ST[64][65];
  int lay = blockIdx.y;
  int g = blockIdx.x >> 3, cc = blockIdx.x & 7;
  int t = threadIdx.x;
#pragma unroll
  for (int i = 0; i < 16; ++i) {
    int idx = i * 256 + t;
    int r1 = idx >> 6, rr = idx & 63;
    ST[rr][r1] = cpcat[(size_t)(lay * 4096 + r1 * 64 + g * 16 + (rr >> 2)) * 12 + 4 + (rr & 3)];
  }
  __syncthreads();
  int lane = t & 63, grp = t >> 6;
  for (int ii = 0; ii < 32; ii += 4) {
    int cb = cc * 128 + grp * 32 + ii;
    const float* v0 = v_w + (size_t)cb * 64;
    const float* v1 = v0 + 64;
    const float* v2 = v0 + 128;
    const float* v3 = v0 + 192;
    float a0 = 0.f, a1 = 0.f, a2 = 0.f, a3 = 0.f;
#pragma unroll 8
    for (int rr = 0; rr < 64; ++rr) {
      float sv = ST[rr][lane];
      a0 += sv * v0[rr]; a1 += sv * v1[rr]; a2 += sv * v2[rr]; a3 += sv * v3[rr];
    }
    size_t ob = ((size_t)lay * 4096 + g * 1024 + cb) * 64 + lane;
    out[ob] = (bf16_t)a0; out[ob + 64] = (bf16_t)a1;
    out[ob + 128] = (bf16_t)a2; out[ob + 192] = (bf16_t)a3;
  }
}

// wpfc2[l][cout][jj] = sum_q CPcat[l][q][jj>>2][8+(jj&3)] * v_w[cout][q]
__global__ __launch_bounds__(256) void wp_fc2_kernel(const float* __restrict__ cpcat,
    const float* __restrict__ v_w, bf16_t* __restrict__ out) {
  __shared__ float SJ[64][65];
  int lay = blockIdx.y;
  int jc = blockIdx.x >> 3, cc = blockIdx.x & 7;
  int t = threadIdx.x;
#pragma unroll
  for (int i = 0; i < 16; ++i) {
    int idx = i * 256 + t;
    int q = idx >> 6, j64 = idx & 63;
    SJ[q][j64] = cpcat[(size_t)(lay * 4096 + q * 64 + jc * 16 + (j64 >> 2)) * 12 + 8 + (j64 & 3)];
  }
  __syncthreads();
  int lane = t & 63, grp = t >> 6;
  for (int ii = 0; ii < 32; ii += 4) {
    int cb = cc * 128 + grp * 32 + ii;
    const float* v0 = v_w + (size_t)cb * 64;
    const float* v1 = v0 + 64;
    const float* v2 = v0 + 128;
    const float* v3 = v0 + 192;
    float a0 = 0.f, a1 = 0.f, a2 = 0.f, a3 = 0.f;
#pragma unroll 8
    for (int q = 0; q < 64; ++q) {
      float sv = SJ[q][lane];
      a0 += sv * v0[q]; a1 += sv * v1[q]; a2 += sv * v2[q]; a3 += sv * v3[q];
    }
    size_t ob = ((size_t)lay * 1024 + cb) * 256 + jc * 64 + lane;
    out[ob] = (bf16_t)a0; out[ob + 256] = (bf16_t)a1;
    out[ob + 512] = (bf16_t)a2; out[ob + 768] = (bf16_t)a3;
  }
}

// LayerNorm over C=1024, write bf16
__global__ __launch_bounds__(256) void ln_kernel(const float* __restrict__ x,
    const float* __restrict__ g, const float* __restrict__ b, bf16_t* __restrict__ out) {
  int row = blockIdx.x;
  int t = threadIdx.x;
  const float4 v = ((const float4*)(x + (size_t)row * 1024))[t];
  float s = v.x + v.y + v.z + v.w;
  float s2 = v.x * v.x + v.y * v.y + v.z * v.z + v.w * v.w;
#pragma unroll
  for (int off = 32; off > 0; off >>= 1) {
    s += __shfl_down(s, off, 64);
    s2 += __shfl_down(s2, off, 64);
  }
  __shared__ float red[8];
  int wv = t >> 6;
  if ((t & 63) == 0) { red[wv * 2] = s; red[wv * 2 + 1] = s2; }
  __syncthreads();
  s = red[0] + red[2] + red[4] + red[6];
  s2 = red[1] + red[3] + red[5] + red[7];
  float mean = s * (1.0f / 1024.0f);
  float var = s2 * (1.0f / 1024.0f) - mean * mean;
  float rstd = rsqrtf(var + 1e-5f);
  const float4 gg = ((const float4*)g)[t];
  const float4 bb = ((const float4*)b)[t];
  union { bf16_t o[4]; uint2 u; } pk;
  pk.o[0] = (bf16_t)((v.x - mean) * rstd * gg.x + bb.x);
  pk.o[1] = (bf16_t)((v.y - mean) * rstd * gg.y + bb.y);
  pk.o[2] = (bf16_t)((v.z - mean) * rstd * gg.z + bb.z);
  pk.o[3] = (bf16_t)((v.w - mean) * rstd * gg.w + bb.w);
  *(uint2*)(out + (size_t)row * 1024 + t * 4) = pk.u;
}

// ---------------- generic bf16 GEMM: C = A[M,K] @ W[N,K]^T ----------------
// 128x128 tile, BK=64, 4 waves (each 64x64), global_load_lds(16B) staging with
// XOR-swizzled LDS (T2), m97 2-barrier K-loop. Templated epilogue.
// M_PREP : out_bf16[rr][col+z*cz] = mfma + wadd_f32  (weight fold, z slices)
// M_QKV  : scatter to q/k/v [B,H,N,D], q pre-scaled
// M_RESID: split-K partial -> atomicAdd into f32 resid (+bias on z==0)
// M_FC1  : + bias, GELU, bf16 out
// z-slicing: A += z*az, W += z*wz, out col += z*cz.

enum { M_PREP = 0, M_QKV = 1, M_RESID = 2, M_FC1 = 3 };

template <int MODE>
__global__ __launch_bounds__(256, 2)
void gemm_bt(const bf16_t* __restrict__ A, int lda,
             const bf16_t* __restrict__ W, int ldw,
             int N, int K, int ldc,
             bf16_t* __restrict__ bout,
             const float* __restrict__ bias,
             const float* __restrict__ wadd, int ldadd,
             float* __restrict__ resid,
             bf16_t* __restrict__ qout, bf16_t* __restrict__ kout, bf16_t* __restrict__ vout,
             int az, int wz, int cz) {
  __shared__ __align__(16) bf16_t Al[128 * 64];
  __shared__ __align__(16) bf16_t Bl[128 * 64];
  int tid = threadIdx.x;
  int w = tid >> 6, l = tid & 63;
  int lr = l & 15, lh = l >> 4;
  int wr = w >> 1, wc = w & 1;
  int m0 = blockIdx.x * 128, n0 = blockIdx.y * 128;
  int zz = blockIdx.z;
  A += (size_t)zz * az;
  W += (size_t)zz * wz;
  int zcol = zz * cz;
  f32x4 acc[4][4];
  const f32x4 fz = {0.f, 0.f, 0.f, 0.f};
#pragma unroll
  for (int i = 0; i < 4; ++i)
#pragma unroll
    for (int j = 0; j < 4; ++j) acc[i][j] = fz;

  int srow = l >> 3;                          // row within 8-row chunk
  int scol = ((l & 7) << 4) ^ (srow << 4);    // pre-swizzled source byte col (T2, via m173)

  for (int k0 = 0; k0 < K; k0 += 64) {
#pragma unroll
    for (int c = 0; c < 8; ++c) {
      int chunk = w * 8 + c;
      if (chunk < 16) {
        int row = m0 + chunk * 8 + srow;
        async16((const char*)(A + (size_t)row * lda + k0) + scol, (char*)Al + chunk * 1024);
      } else {
        int ch = chunk - 16;
        int row = n0 + ch * 8 + srow;
        async16((const char*)(W + (size_t)row * ldw + k0) + scol, (char*)Bl + ch * 1024);
      }
    }
    __syncthreads();
#pragma unroll
    for (int kk = 0; kk < 2; ++kk) {
      bf16x8 af[4], bfv[4];
#pragma unroll
      for (int i = 0; i < 4; ++i) {
        int ar = wr * 64 + i * 16 + lr;
        af[i] = *(const bf16x8*)((const char*)Al + ar * 128 + (((lh << 4) + (kk << 6)) ^ ((ar & 7) << 4)));
        int br = wc * 64 + i * 16 + lr;
        bfv[i] = *(const bf16x8*)((const char*)Bl + br * 128 + (((lh << 4) + (kk << 6)) ^ ((br & 7) << 4)));
      }
#pragma unroll
      for (int i = 0; i < 4; ++i)
#pragma unroll
        for (int j = 0; j < 4; ++j) acc[i][j] = mfma16(af[i], bfv[j], acc[i][j]);
    }
    __syncthreads();
  }

  // epilogue — C/D layout: col = lane&15, row = (lane>>4)*4 + reg  [m89]
#pragma unroll
  for (int i = 0; i < 4; ++i) {
    int row0 = m0 + wr * 64 + i * 16 + lh * 4;
#pragma unroll
    for (int j = 0; j < 4; ++j) {
      int col = n0 + wc * 64 + j * 16 + lr;
#pragma unroll
      for (int r = 0; r < 4; ++r) {
        int rr = row0 + r;
        float v = acc[i][j][r];
        if constexpr (MODE == M_PREP) {
          int colw = col + zcol;
          v += wadd[(size_t)rr * ldadd + colw];
          bout[(size_t)rr * ldc + colw] = (bf16_t)v;
        } else if constexpr (MODE == M_QKV) {
          int which = col >> 10, crem = col & 1023;
          int hh = crem >> 6, dd = crem & 63;
          int bb = rr >> 10, nn = rr & 1023;
          size_t di = ((size_t)(bb * 16 + hh) * 1024 + nn) * 64 + dd;
          if (which == 0) qout[di] = (bf16_t)(v * 0.125f);  // q pre-scaled by D^-0.5
          else if (which == 1) kout[di] = (bf16_t)v;
          else vout[di] = (bf16_t)v;
        } else if constexpr (MODE == M_RESID) {
          if (zz == 0) v += bias[col];
          atomicAdd(&resid[(size_t)rr * 1024 + col], v);
        } else if constexpr (MODE == M_FC1) {
          v += bias[col];
          bout[(size_t)rr * ldc + col] = (bf16_t)gelu_f(v);
        }
      }
    }
  }
}

// ---------------- flash attention (causal), bf16 MFMA ----------------
// grid (N/64, B*H); 4 waves, each 16 q-rows; KV tiles of 64; K & V^T staged in
// XOR-swizzled LDS; P round-trips via padded per-wave LDS (stride 72 elems).

__global__ __launch_bounds__(256, 2)
void attn_kernel(const bf16_t* __restrict__ qb, const bf16_t* __restrict__ kb,
                 const bf16_t* __restrict__ vb, bf16_t* __restrict__ out) {
  __shared__ __align__(16) bf16_t Kl[64 * 64];
  __shared__ __align__(16) bf16_t Vl[64 * 64];      // V transposed: [d][key]
  __shared__ __align__(16) bf16_t Pl[4][16 * 72];
  int tid = threadIdx.x;
  int w = tid >> 6, l = tid & 63;
  int lr = l & 15, lh = l >> 4;
  int bh = blockIdx.y;
  int q0 = blockIdx.x * 64;
  const size_t base = (size_t)bh * 1024 * 64;

  const bf16_t* qrow_ptr = qb + base + (size_t)(q0 + w * 16 + lr) * 64;
  bf16x8 qf0 = *(const bf16x8*)(qrow_ptr + lh * 8);
  bf16x8 qf1 = *(const bf16x8*)(qrow_ptr + 32 + lh * 8);

  f32x4 acc_o[4];
  float m_run[4], l_run[4];
  const f32x4 fz = {0.f, 0.f, 0.f, 0.f};
#pragma unroll
  for (int i = 0; i < 4; ++i) { acc_o[i] = fz; m_run[i] = -1e30f; l_run[i] = 0.f; }

  int nt = blockIdx.x + 1;
  int srow = tid >> 2, sseg = tid & 3;

  for (int t = 0; t < nt; ++t) {
    int k0 = t * 64;
    __syncthreads();
    {  // stage K tile [key][d] (swizzled) and V^T tile [d][key] (swizzled)
      const bf16_t* ksrc = kb + base + (size_t)(k0 + srow) * 64 + sseg * 16;
      uint4 v0 = *(const uint4*)(ksrc);
      uint4 v1 = *(const uint4*)(ksrc + 8);
      int c0 = sseg * 32;
      *(uint4*)((char*)Kl + srow * 128 + (c0 ^ ((srow & 7) << 4))) = v0;
      *(uint4*)((char*)Kl + srow * 128 + ((c0 + 16) ^ ((srow & 7) << 4))) = v1;
      const bf16_t* vsrc = vb + base + (size_t)(k0 + srow) * 64 + sseg * 16;
      union { uint4 u[2]; bf16_t e[16]; } tv;
      tv.u[0] = *(const uint4*)(vsrc);
      tv.u[1] = *(const uint4*)(vsrc + 8);
#pragma unroll
      for (int j = 0; j < 16; ++j) {
        int d = sseg * 16 + j;
        *(bf16_t*)((char*)Vl + d * 128 + ((srow * 2) ^ ((d & 7) << 4))) = tv.e[j];
      }
    }
    __syncthreads();

    // S = Q K^T  (16q x 64keys per wave)
    f32x4 s[4];
#pragma unroll
    for (int kg = 0; kg < 4; ++kg) {
      int krow = kg * 16 + lr;
      const char* kbase = (const char*)Kl + krow * 128;
      int sw = (krow & 7) << 4;
      bf16x8 k0f = *(const bf16x8*)(kbase + ((lh * 16) ^ sw));
      bf16x8 k1f = *(const bf16x8*)(kbase + ((lh * 16 + 64) ^ sw));
      f32x4 z = fz;
      z = mfma16(qf0, k0f, z);
      z = mfma16(qf1, k1f, z);
      s[kg] = z;
    }

    // causal mask + online softmax (rows spread over 16-lane groups)
#pragma unroll
    for (int r = 0; r < 4; ++r) {
      int qrow = q0 + w * 16 + lh * 4 + r;
#pragma unroll
      for (int kg = 0; kg < 4; ++kg) {
        int key = k0 + kg * 16 + lr;
        if (key > qrow) s[kg][r] = -1e30f;
      }
      float mx = fmaxf(fmaxf(s[0][r], s[1][r]), fmaxf(s[2][r], s[3][r]));
      mx = fmaxf(mx, __shfl_xor(mx, 1, 64));
      mx = fmaxf(mx, __shfl_xor(mx, 2, 64));
      mx = fmaxf(mx, __shfl_xor(mx, 4, 64));
      mx = fmaxf(mx, __shfl_xor(mx, 8, 64));
      float mn = fmaxf(m_run[r], mx);
      float al = __expf(m_run[r] - mn);
      m_run[r] = mn;
      float sum = 0.f;
#pragma unroll
      for (int kg = 0; kg < 4; ++kg) {
        float pv = __expf(s[kg][r] - mn);
        s[kg][r] = pv;
        sum += pv;
      }
      sum += __shfl_xor(sum, 1, 64);
      sum += __shfl_xor(sum, 2, 64);
      sum += __shfl_xor(sum, 4, 64);
      sum += __shfl_xor(sum, 8, 64);
      l_run[r] = l_run[r] * al + sum;
#pragma unroll
      for (int dg = 0; dg < 4; ++dg) acc_o[dg][r] *= al;
#pragma unroll
      for (int kg = 0; kg < 4; ++kg)
        Pl[w][(lh * 4 + r) * 72 + kg * 16 + lr] = (bf16_t)s[kg][r];
    }

    // barrier: P rows are read by different lanes than wrote them
    __syncthreads();

    // O += P V
#pragma unroll
    for (int dg = 0; dg < 4; ++dg) {
      int vrow = dg * 16 + lr;
      const char* vbase = (const char*)Vl + vrow * 128;
      int sw = (vrow & 7) << 4;
#pragma unroll
      for (int kb2 = 0; kb2 < 2; ++kb2) {
        bf16x8 pf = *(const bf16x8*)(&Pl[w][lr * 72 + lh * 8 + kb2 * 32]);
        bf16x8 vf = *(const bf16x8*)(vbase + ((lh * 16 + kb2 * 64) ^ sw));
        acc_o[dg] = mfma16(pf, vf, acc_o[dg]);
      }
    }
  }

  int b = bh >> 4, h = bh & 15;
#pragma unroll
  for (int dg = 0; dg < 4; ++dg) {
    int col = h * 64 + dg * 16 + lr;
#pragma unroll
    for (int r = 0; r < 4; ++r) {
      int n = q0 + w * 16 + lh * 4 + r;
      out[((size_t)b * 1024 + n) * 1024 + col] = (bf16_t)(acc_o[dg][r] / l_run[r]);
    }
  }
}

// ---------------- host ----------------

template <int MODE>
static inline void gl(hipStream_t st, int M, int N, int K,
                     const bf16_t* A, int lda, const bf16_t* W, int ldw, int ldc,
                     bf16_t* bout, const float* bias, const float* wadd, int ldadd,
                     float* resid,
                     bf16_t* qo = nullptr, bf16_t* ko = nullptr, bf16_t* vo = nullptr,
                     int az = 0, int wz = 0, int cz = 0, int gz = 1) {
  gemm_bt<MODE><<<dim3(M / 128, N / 128, gz), 256, 0, st>>>(
      A, lda, W, ldw, N, K, ldc, bout, bias, wadd, ldadd, resid, qo, ko, vo, az, wz, cz);
}

extern "C" void kernel_launch(void* const* d_in, const int* in_sizes, int n_in,
                              void* d_out, int out_size, void* d_ws, size_t ws_size,
                              hipStream_t stream) {
  const float* x_in   = (const float*)d_in[0];
  const float* ln1_g  = (const float*)d_in[2];
  const float* ln1_b  = (const float*)d_in[3];
  const float* qkv_w  = (const float*)d_in[4];
  const float* proj_w = (const float*)d_in[5];
  const float* proj_b = (const float*)d_in[6];
  const float* cp_att = (const float*)d_in[7];
  const float* ln2_g  = (const float*)d_in[8];
  const float* ln2_b  = (const float*)d_in[9];
  const float* fc1_w  = (const float*)d_in[10];
  const float* fc1_b  = (const float*)d_in[11];
  const float* fc2_w  = (const float*)d_in[12];
  const float* fc2_b  = (const float*)d_in[13];
  const float* mlp_cp = (const float*)d_in[14];
  const float* u_w    = (const float*)d_in[15];
  const float* v_w    = (const float*)d_in[16];
  const float* cp_c   = (const float*)d_in[17];
  float* xbuf = (float*)d_out;  // running residual stream

  char* p = (char*)d_ws;
  auto carve = [&](size_t bytes) { char* r = p; p += (bytes + 255) & ~(size_t)255; return r; };
  bf16_t* wl    = (bf16_t*)carve(12582912ull * 2);  // per-layer folded bf16 weights
  bf16_t* uwT   = (bf16_t*)carve(65536ull * 2);     // u_w^T [1024][64]
  float*  cpcat = (float*) carve(196608ull * 4);
  bf16_t* wpatt = (bf16_t*)carve(1048576ull * 2);   // [L][4][1024][64]
  bf16_t* wpfc1 = (bf16_t*)carve(1048576ull * 2);   // [L][4096][64]
  bf16_t* wpfc2 = (bf16_t*)carve(1048576ull * 2);   // [L][1024][256]
  bf16_t* hbuf  = (bf16_t*)carve(2097152ull * 2);
  bf16_t* qbuf  = (bf16_t*)carve(2097152ull * 2);
  bf16_t* kbuf  = (bf16_t*)carve(2097152ull * 2);
  bf16_t* vbuf  = (bf16_t*)carve(2097152ull * 2);
  bf16_t* aout  = (bf16_t*)carve(2097152ull * 2);
  bf16_t* abuf  = (bf16_t*)carve(8388608ull * 2);

  hipMemcpyAsync(xbuf, x_in, (size_t)2048 * 1024 * 4, hipMemcpyDeviceToDevice, stream);
  utrans_kernel<<<16, 256, 0, stream>>>(u_w, uwT);
  cpcat_kernel<<<64, 256, 0, stream>>>(cp_c, cp_att, mlp_cp, cpcat);
  wp_att_kernel<<<dim3(32, 4), 256, 0, stream>>>(cpcat, v_w, wpatt);
  wp_fc1_kernel<<<dim3(32, 4), 256, 0, stream>>>(cpcat, v_w, wpfc1);
  wp_fc2_kernel<<<dim3(32, 4), 256, 0, stream>>>(cpcat, v_w, wpfc2);

  for (int l = 0; l < 4; ++l) {
    bf16_t* wqkv  = wl;
    bf16_t* wproj = wl + 3145728;
    bf16_t* wfc1  = wl + 4194304;
    bf16_t* wfc2  = wl + 8388608;

    // ---- weight fold: W_eff = W + u_w^T @ P  (K=64 prep GEMMs) ----
    gl<M_PREP>(stream, 3072, 1024, 64, wpatt + (size_t)l * 262144, 64, uwT, 64, 1024,
               wqkv, nullptr, qkv_w + (size_t)l * 3145728, 1024, nullptr);
    gl<M_PREP>(stream, 1024, 1024, 64, wpatt + (size_t)l * 262144 + 196608, 64, uwT, 64, 1024,
               wproj, nullptr, proj_w + (size_t)l * 1048576, 1024, nullptr);
    gl<M_PREP>(stream, 4096, 1024, 64, wpfc1 + (size_t)l * 262144, 64, uwT, 64, 1024,
               wfc1, nullptr, fc1_w + (size_t)l * 4194304, 1024, nullptr);
    gl<M_PREP>(stream, 1024, 1024, 64, wpfc2 + (size_t)l * 262144, 256, uwT, 64, 4096,
               wfc2, nullptr, fc2_w + (size_t)l * 4194304, 4096, nullptr,
               nullptr, nullptr, nullptr, 64, 0, 1024, 4);

    // ---- attention block ----
    ln_kernel<<<2048, 256, 0, stream>>>(xbuf, ln1_g + l * 1024, ln1_b + l * 1024, hbuf);
    gl<M_QKV>(stream, 2048, 3072, 1024, hbuf, 1024, wqkv, 1024, 0,
              nullptr, nullptr, nullptr, 0, nullptr, qbuf, kbuf, vbuf);
    attn_kernel<<<dim3(16, 32), 256, 0, stream>>>(qbuf, kbuf, vbuf, aout);
    // proj: split-K=2 (2x512), atomic combine into resid
    gl<M_RESID>(stream, 2048, 1024, 512, aout, 1024, wproj, 1024, 0,
                nullptr, proj_b + l * 1024, nullptr, 0, xbuf,
                nullptr, nullptr, nullptr, 512, 512, 0, 2);

    // ---- ffn block ----
    ln_kernel<<<2048, 256, 0, stream>>>(xbuf, ln2_g + l * 1024, ln2_b + l * 1024, hbuf);
    gl<M_FC1>(stream, 2048, 4096, 1024, hbuf, 1024, wfc1, 1024, 4096,
              abuf, fc1_b + l * 4096, nullptr, 0, nullptr);
    // fc2: split-K=4 (4x1024), atomic combine into resid
    gl<M_RESID>(stream, 2048, 1024, 1024, abuf, 4096, wfc2, 4096, 0,
                nullptr, fc2_b + l * 1024, nullptr, 0, xbuf,
                nullptr, nullptr, nullptr, 1024, 1024, 0, 4);
  }
}

// Round 7
// 1105.824 us; speedup vs baseline: 1.0908x; 1.0908x over previous
//
#include <hip/hip_runtime.h>
#include <cstdint>
#include <cstddef>

// CP_TransformerDecoder on MI355X — round 7: pipelined GEMM K-loop.
// Round-6 counters: main GEMMs at MfmaUtil ~11%, occ 15% — bound by the
// per-K-step vmcnt(0) drain that __syncthreads() forces. Switch the K-loop to
// a 2-phase double-buffered schedule: STAGE(next) issued before compute,
// counted s_waitcnt vmcnt(8) (never 0 mid-loop), raw s_barrier (no compiler
// drain). Also batch the 16 per-layer weight-fold GEMMs into 4 dispatches
// (virtual-tile decode), removing 12 serialized launches.

typedef __bf16 bf16_t;
typedef __bf16 bf16x8 __attribute__((ext_vector_type(8)));
typedef float  f32x4  __attribute__((ext_vector_type(4)));

#define DEVI __device__ __forceinline__

DEVI f32x4 mfma16(bf16x8 a, bf16x8 b, f32x4 c) {
  return __builtin_amdgcn_mfma_f32_16x16x32_bf16(a, b, c, 0, 0, 0);
}

DEVI void async16(const void* g, void* l) {
  __builtin_amdgcn_global_load_lds((const __attribute__((address_space(1))) void*)g,
                                   (__attribute__((address_space(3))) void*)l, 16, 0, 0);
}

DEVI float gelu_f(float v) { return 0.5f * v * (1.0f + erff(v * 0.70710678118654752440f)); }

// ---------------- preprocessing ----------------

// u_wT[c][r] = u_w[r][c]  (bf16), LDS-tiled transpose
__global__ __launch_bounds__(256) void utrans_kernel(const float* __restrict__ u_w,
                                                     bf16_t* __restrict__ out) {
  __shared__ float T[64][65];
  int t = threadIdx.x, c0 = blockIdx.x * 64;
#pragma unroll
  for (int i = 0; i < 16; ++i) {
    int idx = i * 256 + t;
    int r = idx >> 6, c = idx & 63;
    T[r][c] = u_w[r * 1024 + c0 + c];
  }
  __syncthreads();
#pragma unroll
  for (int i = 0; i < 16; ++i) {
    int idx = i * 256 + t;
    int c = idx >> 6, r = idx & 63;
    out[(size_t)(c0 + c) * 64 + r] = (bf16_t)T[r][c];
  }
}

// CPcat[l][r1][r2][f], f=0..3 from cp_att, f=4..11 from mlp_cp
__global__ __launch_bounds__(256) void cpcat_kernel(const float* __restrict__ cp_c,
    const float* __restrict__ cp_att, const float* __restrict__ mlp_cp, float* __restrict__ cpcat) {
  int idx = blockIdx.x * 256 + threadIdx.x;  // 16384 = L*64*64
  int lay = idx >> 12, ab = idx & 4095;
  const float* crow = cp_c + (size_t)ab * 64;
  float acc[12];
#pragma unroll
  for (int f = 0; f < 12; ++f) acc[f] = 0.f;
  for (int r = 0; r < 64; ++r) {
    float cv = crow[r];
    const float* wa = cp_att + lay * 256 + r * 4;
    const float* wm = mlp_cp + lay * 512 + r * 8;
#pragma unroll
    for (int f = 0; f < 4; ++f) acc[f] += cv * wa[f];
#pragma unroll
    for (int f = 0; f < 8; ++f) acc[4 + f] += cv * wm[f];
  }
  float* o = cpcat + (size_t)idx * 12;
#pragma unroll
  for (int f = 0; f < 12; ++f) o[f] = acc[f];
}

// wpatt[l][f][cout][r1] = sum_r2 CPcat[l][r1][r2][f] * v_w[cout][r2]
__global__ __launch_bounds__(256) void wp_att_kernel(const float* __restrict__ cpcat,
    const float* __restrict__ v_w, bf16_t* __restrict__ out) {
  __shared__ float ST[64][65];
  int lay = blockIdx.y;
  int f = blockIdx.x >> 3, cc = blockIdx.x & 7;
  int t = threadIdx.x;
#pragma unroll
  for (int i = 0; i < 16; ++i) {
    int idx = i * 256 + t;
    int r1 = idx >> 6, r2 = idx & 63;
    ST[r2][r1] = cpcat[(size_t)(lay * 4096 + r1 * 64 + r2) * 12 + f];
  }
  __syncthreads();
  int lane = t & 63, grp = t >> 6;
  for (int ii = 0; ii < 32; ii += 4) {
    int cb = cc * 128 + grp * 32 + ii;
    const float* v0 = v_w + (size_t)cb * 64;
    const float* v1 = v0 + 64;
    const float* v2 = v0 + 128;
    const float* v3 = v0 + 192;
    float a0 = 0.f, a1 = 0.f, a2 = 0.f, a3 = 0.f;
#pragma unroll 8
    for (int r2 = 0; r2 < 64; ++r2) {
      float sv = ST[r2][lane];
      a0 += sv * v0[r2]; a1 += sv * v1[r2]; a2 += sv * v2[r2]; a3 += sv * v3[r2];
    }
    size_t ob = ((size_t)(lay * 4 + f) * 1024 + cb) * 64 + lane;
    out[ob] = (bf16_t)a0; out[ob + 64] = (bf16_t)a1;
    out[ob + 128] = (bf16_t)a2; out[ob + 192] = (bf16_t)a3;
  }
}

// wpfc1[l][g*1024+cout][r1] = sum_rr CPcat[l][r1][g*16+(rr>>2)][4+(rr&3)] * v_w[cout][rr]
__global__ __launch_bounds__(256) void wp_fc1_kernel(const float* __restrict__ cpcat,
    const float* __restrict__ v_w, bf16_t* __restrict__ out) {
  __shared__ float ST[64][65];
  int lay = blockIdx.y;
  int g = blockIdx.x >> 3, cc = blockIdx.x & 7;
  int t = threadIdx.x;
#pragma unroll
  for (int i = 0; i < 16; ++i) {
    int idx = i * 256 + t;
    int r1 = idx >> 6, rr = idx & 63;
    ST[rr][r1] = cpcat[(size_t)(lay * 4096 + r1 * 64 + g * 16 + (rr >> 2)) * 12 + 4 + (rr & 3)];
  }
  __syncthreads();
  int lane = t & 63, grp = t >> 6;
  for (int ii = 0; ii < 32; ii += 4) {
    int cb = cc * 128 + grp * 32 + ii;
    const float* v0 = v_w + (size_t)cb * 64;
    const float* v1 = v0 + 64;
    const float* v2 = v0 + 128;
    const float* v3 = v0 + 192;
    float a0 = 0.f, a1 = 0.f, a2 = 0.f, a3 = 0.f;
#pragma unroll 8
    for (int rr = 0; rr < 64; ++rr) {
      float sv = ST[rr][lane];
      a0 += sv * v0[rr]; a1 += sv * v1[rr]; a2 += sv * v2[rr]; a3 += sv * v3[rr];
    }
    size_t ob = ((size_t)lay * 4096 + g * 1024 + cb) * 64 + lane;
    out[ob] = (bf16_t)a0; out[ob + 64] = (bf16_t)a1;
    out[ob + 128] = (bf16_t)a2; out[ob + 192] = (bf16_t)a3;
  }
}

// wpfc2[l][cout][jj] = sum_q CPcat[l][q][jj>>2][8+(jj&3)] * v_w[cout][q]
__global__ __launch_bounds__(256) void wp_fc2_kernel(const float* __restrict__ cpcat,
    const float* __restrict__ v_w, bf16_t* __restrict__ out) {
  __shared__ float SJ[64][65];
  int lay = blockIdx.y;
  int jc = blockIdx.x >> 3, cc = blockIdx.x & 7;
  int t = threadIdx.x;
#pragma unroll
  for (int i = 0; i < 16; ++i) {
    int idx = i * 256 + t;
    int q = idx >> 6, j64 = idx & 63;
    SJ[q][j64] = cpcat[(size_t)(lay * 4096 + q * 64 + jc * 16 + (j64 >> 2)) * 12 + 8 + (j64 & 3)];
  }
  __syncthreads();
  int lane = t & 63, grp = t >> 6;
  for (int ii = 0; ii < 32; ii += 4) {
    int cb = cc * 128 + grp * 32 + ii;
    const float* v0 = v_w + (size_t)cb * 64;
    const float* v1 = v0 + 64;
    const float* v2 = v0 + 128;
    const float* v3 = v0 + 192;
    float a0 = 0.f, a1 = 0.f, a2 = 0.f, a3 = 0.f;
#pragma unroll 8
    for (int q = 0; q < 64; ++q) {
      float sv = SJ[q][lane];
      a0 += sv * v0[q]; a1 += sv * v1[q]; a2 += sv * v2[q]; a3 += sv * v3[q];
    }
    size_t ob = ((size_t)lay * 1024 + cb) * 256 + jc * 64 + lane;
    out[ob] = (bf16_t)a0; out[ob + 256] = (bf16_t)a1;
    out[ob + 512] = (bf16_t)a2; out[ob + 768] = (bf16_t)a3;
  }
}

// LayerNorm over C=1024, write bf16
__global__ __launch_bounds__(256) void ln_kernel(const float* __restrict__ x,
    const float* __restrict__ g, const float* __restrict__ b, bf16_t* __restrict__ out) {
  int row = blockIdx.x;
  int t = threadIdx.x;
  const float4 v = ((const float4*)(x + (size_t)row * 1024))[t];
  float s = v.x + v.y + v.z + v.w;
  float s2 = v.x * v.x + v.y * v.y + v.z * v.z + v.w * v.w;
#pragma unroll
  for (int off = 32; off > 0; off >>= 1) {
    s += __shfl_down(s, off, 64);
    s2 += __shfl_down(s2, off, 64);
  }
  __shared__ float red[8];
  int wv = t >> 6;
  if ((t & 63) == 0) { red[wv * 2] = s; red[wv * 2 + 1] = s2; }
  __syncthreads();
  s = red[0] + red[2] + red[4] + red[6];
  s2 = red[1] + red[3] + red[5] + red[7];
  float mean = s * (1.0f / 1024.0f);
  float var = s2 * (1.0f / 1024.0f) - mean * mean;
  float rstd = rsqrtf(var + 1e-5f);
  const float4 gg = ((const float4*)g)[t];
  const float4 bb = ((const float4*)b)[t];
  union { bf16_t o[4]; uint2 u; } pk;
  pk.o[0] = (bf16_t)((v.x - mean) * rstd * gg.x + bb.x);
  pk.o[1] = (bf16_t)((v.y - mean) * rstd * gg.y + bb.y);
  pk.o[2] = (bf16_t)((v.z - mean) * rstd * gg.z + bb.z);
  pk.o[3] = (bf16_t)((v.w - mean) * rstd * gg.w + bb.w);
  *(uint2*)(out + (size_t)row * 1024 + t * 4) = pk.u;
}

// ---------------- batched weight-fold: W_eff = W + u_w^T @ P ----------------
// One dispatch per layer, virtual-tile decode over {qkv(24), proj(8), fc1(32),
// fc2(8x4z)} m-tiles x 8 n-tiles. K=64 single step.

struct PrepArgs {
  const bf16_t* uwT;
  const bf16_t* wpatt;  // layer base [4][1024][64]; proj slice at +196608
  const bf16_t* wpfc1;  // [4096][64]
  const bf16_t* wpfc2;  // [1024][256]
  const float* qkvw; const float* projw; const float* fc1w; const float* fc2w;
  bf16_t* wqkv; bf16_t* wproj; bf16_t* wfc1; bf16_t* wfc2;
};

__global__ __launch_bounds__(256, 2)
void prep_all_kernel(PrepArgs a) {
  __shared__ __align__(16) bf16_t Al[128 * 64];
  __shared__ __align__(16) bf16_t Bl[128 * 64];
  int mi = blockIdx.x, n0 = blockIdx.y * 128;
  const bf16_t* A; const float* wadd; bf16_t* outp;
  int m0, ldo = 1024, lda = 64, zcol = 0;
  if (mi < 24)      { A = a.wpatt;          m0 = mi * 128;        wadd = a.qkvw; outp = a.wqkv; }
  else if (mi < 32) { A = a.wpatt + 196608; m0 = (mi - 24) * 128; wadd = a.projw; outp = a.wproj; }
  else if (mi < 64) { A = a.wpfc1;          m0 = (mi - 32) * 128; wadd = a.fc1w; outp = a.wfc1; }
  else {
    int q = mi - 64, z = q >> 3;
    A = a.wpfc2 + z * 64; m0 = (q & 7) * 128; wadd = a.fc2w; outp = a.wfc2;
    ldo = 4096; lda = 256; zcol = z * 1024;
  }
  int tid = threadIdx.x;
  int w = tid >> 6, l = tid & 63;
  int lr = l & 15, lh = l >> 4;
  int wr = w >> 1, wc = w & 1;
  int srow = l >> 3;
  int scol = ((l & 7) << 4) ^ (srow << 4);
#pragma unroll
  for (int c = 0; c < 8; ++c) {
    int chunk = w * 8 + c;
    if (chunk < 16) {
      int row = m0 + chunk * 8 + srow;
      async16((const char*)(A + (size_t)row * lda) + scol, (char*)Al + chunk * 1024);
    } else {
      int ch = chunk - 16;
      int row = n0 + ch * 8 + srow;
      async16((const char*)(a.uwT + (size_t)row * 64) + scol, (char*)Bl + ch * 1024);
    }
  }
  __syncthreads();
  f32x4 acc[4][4];
  const f32x4 fz = {0.f, 0.f, 0.f, 0.f};
#pragma unroll
  for (int i = 0; i < 4; ++i)
#pragma unroll
    for (int j = 0; j < 4; ++j) acc[i][j] = fz;
#pragma unroll
  for (int kk = 0; kk < 2; ++kk) {
    bf16x8 af[4], bfv[4];
#pragma unroll
    for (int i = 0; i < 4; ++i) {
      int ar = wr * 64 + i * 16 + lr;
      af[i] = *(const bf16x8*)((const char*)Al + ar * 128 + (((lh << 4) + (kk << 6)) ^ ((ar & 7) << 4)));
      int br = wc * 64 + i * 16 + lr;
      bfv[i] = *(const bf16x8*)((const char*)Bl + br * 128 + (((lh << 4) + (kk << 6)) ^ ((br & 7) << 4)));
    }
#pragma unroll
    for (int i = 0; i < 4; ++i)
#pragma unroll
      for (int j = 0; j < 4; ++j) acc[i][j] = mfma16(af[i], bfv[j], acc[i][j]);
  }
#pragma unroll
  for (int i = 0; i < 4; ++i) {
    int row0 = m0 + wr * 64 + i * 16 + lh * 4;
#pragma unroll
    for (int j = 0; j < 4; ++j) {
      int colw = n0 + wc * 64 + j * 16 + lr + zcol;
#pragma unroll
      for (int r = 0; r < 4; ++r) {
        int rr = row0 + r;
        float v = acc[i][j][r] + wadd[(size_t)rr * ldo + colw];
        outp[(size_t)rr * ldo + colw] = (bf16_t)v;
      }
    }
  }
}

// ---------------- generic bf16 GEMM: C = A[M,K] @ W[N,K]^T ----------------
// 128x128 tile, BK=64, 4 waves, global_load_lds(16B) staging, XOR-swizzled LDS
// (T2). 2-phase double-buffered K-loop: STAGE(next) issued before compute,
// counted s_waitcnt vmcnt(8), raw s_barrier (no compiler vmcnt(0) drain).
// M_QKV  : scatter to q/k/v [B,H,N,D], q pre-scaled
// M_RESID: split-K partial -> atomicAdd into f32 resid (+bias on z==0)
// M_FC1  : + bias, GELU, bf16 out

enum { M_QKV = 0, M_RESID = 1, M_FC1 = 2 };

template <int MODE>
__global__ __launch_bounds__(256, 2)
void gemm_bt(const bf16_t* __restrict__ A, int lda,
             const bf16_t* __restrict__ W, int ldw,
             int N, int K, int ldc,
             bf16_t* __restrict__ bout,
             const float* __restrict__ bias,
             float* __restrict__ resid,
             bf16_t* __restrict__ qout, bf16_t* __restrict__ kout, bf16_t* __restrict__ vout,
             int az, int wz) {
  __shared__ __align__(16) bf16_t Al[2][128 * 64];
  __shared__ __align__(16) bf16_t Bl[2][128 * 64];
  int tid = threadIdx.x;
  int w = tid >> 6, l = tid & 63;
  int lr = l & 15, lh = l >> 4;
  int wr = w >> 1, wc = w & 1;
  int m0 = blockIdx.x * 128, n0 = blockIdx.y * 128;
  int zz = blockIdx.z;
  A += (size_t)zz * az;
  W += (size_t)zz * wz;
  f32x4 acc[4][4];
  const f32x4 fz = {0.f, 0.f, 0.f, 0.f};
#pragma unroll
  for (int i = 0; i < 4; ++i)
#pragma unroll
    for (int j = 0; j < 4; ++j) acc[i][j] = fz;

  int srow = l >> 3;                          // row within 8-row chunk
  int scol = ((l & 7) << 4) ^ (srow << 4);    // pre-swizzled source byte col (T2)

  auto STAGE = [&](int buf, int k0) {
#pragma unroll
    for (int c = 0; c < 8; ++c) {
      int chunk = w * 8 + c;
      if (chunk < 16) {
        int row = m0 + chunk * 8 + srow;
        async16((const char*)(A + (size_t)row * lda + k0) + scol, (char*)Al[buf] + chunk * 1024);
      } else {
        int ch = chunk - 16;
        int row = n0 + ch * 8 + srow;
        async16((const char*)(W + (size_t)row * ldw + k0) + scol, (char*)Bl[buf] + ch * 1024);
      }
    }
  };

  int nt = K >> 6;
  STAGE(0, 0);
  for (int t = 0; t < nt; ++t) {
    int cur = t & 1;
    if (t + 1 < nt) {
      STAGE(cur ^ 1, (t + 1) << 6);
      asm volatile("s_waitcnt vmcnt(8)" ::: "memory");  // previous batch landed
    } else {
      asm volatile("s_waitcnt vmcnt(0)" ::: "memory");
    }
    __builtin_amdgcn_s_barrier();   // all waves' current-buf loads complete
#pragma unroll
    for (int kk = 0; kk < 2; ++kk) {
      bf16x8 af[4], bfv[4];
#pragma unroll
      for (int i = 0; i < 4; ++i) {
        int ar = wr * 64 + i * 16 + lr;
        af[i] = *(const bf16x8*)((const char*)Al[cur] + ar * 128 + (((lh << 4) + (kk << 6)) ^ ((ar & 7) << 4)));
        int br = wc * 64 + i * 16 + lr;
        bfv[i] = *(const bf16x8*)((const char*)Bl[cur] + br * 128 + (((lh << 4) + (kk << 6)) ^ ((br & 7) << 4)));
      }
#pragma unroll
      for (int i = 0; i < 4; ++i)
#pragma unroll
        for (int j = 0; j < 4; ++j) acc[i][j] = mfma16(af[i], bfv[j], acc[i][j]);
    }
    __builtin_amdgcn_s_barrier();   // reads done before next STAGE overwrites
  }

  // epilogue — C/D layout: col = lane&15, row = (lane>>4)*4 + reg  [m89]
#pragma unroll
  for (int i = 0; i < 4; ++i) {
    int row0 = m0 + wr * 64 + i * 16 + lh * 4;
#pragma unroll
    for (int j = 0; j < 4; ++j) {
      int col = n0 + wc * 64 + j * 16 + lr;
#pragma unroll
      for (int r = 0; r < 4; ++r) {
        int rr = row0 + r;
        float v = acc[i][j][r];
        if constexpr (MODE == M_QKV) {
          int which = col >> 10, crem = col & 1023;
          int hh = crem >> 6, dd = crem & 63;
          int bb = rr >> 10, nn = rr & 1023;
          size_t di = ((size_t)(bb * 16 + hh) * 1024 + nn) * 64 + dd;
          if (which == 0) qout[di] = (bf16_t)(v * 0.125f);  // q pre-scaled by D^-0.5
          else if (which == 1) kout[di] = (bf16_t)v;
          else vout[di] = (bf16_t)v;
        } else if constexpr (MODE == M_RESID) {
          if (zz == 0) v += bias[col];
          atomicAdd(&resid[(size_t)rr * 1024 + col], v);
        } else if constexpr (MODE == M_FC1) {
          v += bias[col];
          bout[(size_t)rr * ldc + col] = (bf16_t)gelu_f(v);
        }
      }
    }
  }
}

// ---------------- flash attention (causal), bf16 MFMA ----------------

__global__ __launch_bounds__(256, 2)
void attn_kernel(const bf16_t* __restrict__ qb, const bf16_t* __restrict__ kb,
                 const bf16_t* __restrict__ vb, bf16_t* __restrict__ out) {
  __shared__ __align__(16) bf16_t Kl[64 * 64];
  __shared__ __align__(16) bf16_t Vl[64 * 64];      // V transposed: [d][key]
  __shared__ __align__(16) bf16_t Pl[4][16 * 72];
  int tid = threadIdx.x;
  int w = tid >> 6, l = tid & 63;
  int lr = l & 15, lh = l >> 4;
  int bh = blockIdx.y;
  int q0 = blockIdx.x * 64;
  const size_t base = (size_t)bh * 1024 * 64;

  const bf16_t* qrow_ptr = qb + base + (size_t)(q0 + w * 16 + lr) * 64;
  bf16x8 qf0 = *(const bf16x8*)(qrow_ptr + lh * 8);
  bf16x8 qf1 = *(const bf16x8*)(qrow_ptr + 32 + lh * 8);

  f32x4 acc_o[4];
  float m_run[4], l_run[4];
  const f32x4 fz = {0.f, 0.f, 0.f, 0.f};
#pragma unroll
  for (int i = 0; i < 4; ++i) { acc_o[i] = fz; m_run[i] = -1e30f; l_run[i] = 0.f; }

  int nt = blockIdx.x + 1;
  int srow = tid >> 2, sseg = tid & 3;

  for (int t = 0; t < nt; ++t) {
    int k0 = t * 64;
    __syncthreads();
    {  // stage K tile [key][d] (swizzled) and V^T tile [d][key] (swizzled)
      const bf16_t* ksrc = kb + base + (size_t)(k0 + srow) * 64 + sseg * 16;
      uint4 v0 = *(const uint4*)(ksrc);
      uint4 v1 = *(const uint4*)(ksrc + 8);
      int c0 = sseg * 32;
      *(uint4*)((char*)Kl + srow * 128 + (c0 ^ ((srow & 7) << 4))) = v0;
      *(uint4*)((char*)Kl + srow * 128 + ((c0 + 16) ^ ((srow & 7) << 4))) = v1;
      const bf16_t* vsrc = vb + base + (size_t)(k0 + srow) * 64 + sseg * 16;
      union { uint4 u[2]; bf16_t e[16]; } tv;
      tv.u[0] = *(const uint4*)(vsrc);
      tv.u[1] = *(const uint4*)(vsrc + 8);
#pragma unroll
      for (int j = 0; j < 16; ++j) {
        int d = sseg * 16 + j;
        *(bf16_t*)((char*)Vl + d * 128 + ((srow * 2) ^ ((d & 7) << 4))) = tv.e[j];
      }
    }
    __syncthreads();

    // S = Q K^T  (16q x 64keys per wave)
    f32x4 s[4];
#pragma unroll
    for (int kg = 0; kg < 4; ++kg) {
      int krow = kg * 16 + lr;
      const char* kbase = (const char*)Kl + krow * 128;
      int sw = (krow & 7) << 4;
      bf16x8 k0f = *(const bf16x8*)(kbase + ((lh * 16) ^ sw));
      bf16x8 k1f = *(const bf16x8*)(kbase + ((lh * 16 + 64) ^ sw));
      f32x4 z = fz;
      z = mfma16(qf0, k0f, z);
      z = mfma16(qf1, k1f, z);
      s[kg] = z;
    }

    // causal mask + online softmax (rows spread over 16-lane groups)
#pragma unroll
    for (int r = 0; r < 4; ++r) {
      int qrow = q0 + w * 16 + lh * 4 + r;
#pragma unroll
      for (int kg = 0; kg < 4; ++kg) {
        int key = k0 + kg * 16 + lr;
        if (key > qrow) s[kg][r] = -1e30f;
      }
      float mx = fmaxf(fmaxf(s[0][r], s[1][r]), fmaxf(s[2][r], s[3][r]));
      mx = fmaxf(mx, __shfl_xor(mx, 1, 64));
      mx = fmaxf(mx, __shfl_xor(mx, 2, 64));
      mx = fmaxf(mx, __shfl_xor(mx, 4, 64));
      mx = fmaxf(mx, __shfl_xor(mx, 8, 64));
      float mn = fmaxf(m_run[r], mx);
      float al = __expf(m_run[r] - mn);
      m_run[r] = mn;
      float sum = 0.f;
#pragma unroll
      for (int kg = 0; kg < 4; ++kg) {
        float pv = __expf(s[kg][r] - mn);
        s[kg][r] = pv;
        sum += pv;
      }
      sum += __shfl_xor(sum, 1, 64);
      sum += __shfl_xor(sum, 2, 64);
      sum += __shfl_xor(sum, 4, 64);
      sum += __shfl_xor(sum, 8, 64);
      l_run[r] = l_run[r] * al + sum;
#pragma unroll
      for (int dg = 0; dg < 4; ++dg) acc_o[dg][r] *= al;
#pragma unroll
      for (int kg = 0; kg < 4; ++kg)
        Pl[w][(lh * 4 + r) * 72 + kg * 16 + lr] = (bf16_t)s[kg][r];
    }

    // barrier: P rows are read by different lanes than wrote them
    __syncthreads();

    // O += P V
#pragma unroll
    for (int dg = 0; dg < 4; ++dg) {
      int vrow = dg * 16 + lr;
      const char* vbase = (const char*)Vl + vrow * 128;
      int sw = (vrow & 7) << 4;
#pragma unroll
      for (int kb2 = 0; kb2 < 2; ++kb2) {
        bf16x8 pf = *(const bf16x8*)(&Pl[w][lr * 72 + lh * 8 + kb2 * 32]);
        bf16x8 vf = *(const bf16x8*)(vbase + ((lh * 16 + kb2 * 64) ^ sw));
        acc_o[dg] = mfma16(pf, vf, acc_o[dg]);
      }
    }
  }

  int b = bh >> 4, h = bh & 15;
#pragma unroll
  for (int dg = 0; dg < 4; ++dg) {
    int col = h * 64 + dg * 16 + lr;
#pragma unroll
    for (int r = 0; r < 4; ++r) {
      int n = q0 + w * 16 + lh * 4 + r;
      out[((size_t)b * 1024 + n) * 1024 + col] = (bf16_t)(acc_o[dg][r] / l_run[r]);
    }
  }
}

// ---------------- host ----------------

template <int MODE>
static inline void gl(hipStream_t st, int M, int N, int K,
                     const bf16_t* A, int lda, const bf16_t* W, int ldw, int ldc,
                     bf16_t* bout, const float* bias, float* resid,
                     bf16_t* qo = nullptr, bf16_t* ko = nullptr, bf16_t* vo = nullptr,
                     int az = 0, int wz = 0, int gz = 1) {
  gemm_bt<MODE><<<dim3(M / 128, N / 128, gz), 256, 0, st>>>(
      A, lda, W, ldw, N, K, ldc, bout, bias, resid, qo, ko, vo, az, wz);
}

extern "C" void kernel_launch(void* const* d_in, const int* in_sizes, int n_in,
                              void* d_out, int out_size, void* d_ws, size_t ws_size,
                              hipStream_t stream) {
  const float* x_in   = (const float*)d_in[0];
  const float* ln1_g  = (const float*)d_in[2];
  const float* ln1_b  = (const float*)d_in[3];
  const float* qkv_w  = (const float*)d_in[4];
  const float* proj_w = (const float*)d_in[5];
  const float* proj_b = (const float*)d_in[6];
  const float* cp_att = (const float*)d_in[7];
  const float* ln2_g  = (const float*)d_in[8];
  const float* ln2_b  = (const float*)d_in[9];
  const float* fc1_w  = (const float*)d_in[10];
  const float* fc1_b  = (const float*)d_in[11];
  const float* fc2_w  = (const float*)d_in[12];
  const float* fc2_b  = (const float*)d_in[13];
  const float* mlp_cp = (const float*)d_in[14];
  const float* u_w    = (const float*)d_in[15];
  const float* v_w    = (const float*)d_in[16];
  const float* cp_c   = (const float*)d_in[17];
  float* xbuf = (float*)d_out;  // running residual stream

  char* p = (char*)d_ws;
  auto carve = [&](size_t bytes) { char* r = p; p += (bytes + 255) & ~(size_t)255; return r; };
  bf16_t* wl    = (bf16_t*)carve(12582912ull * 2);  // per-layer folded bf16 weights
  bf16_t* uwT   = (bf16_t*)carve(65536ull * 2);     // u_w^T [1024][64]
  float*  cpcat = (float*) carve(196608ull * 4);
  bf16_t* wpatt = (bf16_t*)carve(1048576ull * 2);   // [L][4][1024][64]
  bf16_t* wpfc1 = (bf16_t*)carve(1048576ull * 2);   // [L][4096][64]
  bf16_t* wpfc2 = (bf16_t*)carve(1048576ull * 2);   // [L][1024][256]
  bf16_t* hbuf  = (bf16_t*)carve(2097152ull * 2);
  bf16_t* qbuf  = (bf16_t*)carve(2097152ull * 2);
  bf16_t* kbuf  = (bf16_t*)carve(2097152ull * 2);
  bf16_t* vbuf  = (bf16_t*)carve(2097152ull * 2);
  bf16_t* aout  = (bf16_t*)carve(2097152ull * 2);
  bf16_t* abuf  = (bf16_t*)carve(8388608ull * 2);

  hipMemcpyAsync(xbuf, x_in, (size_t)2048 * 1024 * 4, hipMemcpyDeviceToDevice, stream);
  utrans_kernel<<<16, 256, 0, stream>>>(u_w, uwT);
  cpcat_kernel<<<64, 256, 0, stream>>>(cp_c, cp_att, mlp_cp, cpcat);
  wp_att_kernel<<<dim3(32, 4), 256, 0, stream>>>(cpcat, v_w, wpatt);
  wp_fc1_kernel<<<dim3(32, 4), 256, 0, stream>>>(cpcat, v_w, wpfc1);
  wp_fc2_kernel<<<dim3(32, 4), 256, 0, stream>>>(cpcat, v_w, wpfc2);

  for (int l = 0; l < 4; ++l) {
    bf16_t* wqkv  = wl;
    bf16_t* wproj = wl + 3145728;
    bf16_t* wfc1  = wl + 4194304;
    bf16_t* wfc2  = wl + 8388608;

    // ---- batched weight fold (1 dispatch) ----
    PrepArgs pa;
    pa.uwT = uwT;
    pa.wpatt = wpatt + (size_t)l * 262144;
    pa.wpfc1 = wpfc1 + (size_t)l * 262144;
    pa.wpfc2 = wpfc2 + (size_t)l * 262144;
    pa.qkvw = qkv_w + (size_t)l * 3145728;
    pa.projw = proj_w + (size_t)l * 1048576;
    pa.fc1w = fc1_w + (size_t)l * 4194304;
    pa.fc2w = fc2_w + (size_t)l * 4194304;
    pa.wqkv = wqkv; pa.wproj = wproj; pa.wfc1 = wfc1; pa.wfc2 = wfc2;
    prep_all_kernel<<<dim3(96, 8), 256, 0, stream>>>(pa);

    // ---- attention block ----
    ln_kernel<<<2048, 256, 0, stream>>>(xbuf, ln1_g + l * 1024, ln1_b + l * 1024, hbuf);
    gl<M_QKV>(stream, 2048, 3072, 1024, hbuf, 1024, wqkv, 1024, 0,
              nullptr, nullptr, nullptr, qbuf, kbuf, vbuf);
    attn_kernel<<<dim3(16, 32), 256, 0, stream>>>(qbuf, kbuf, vbuf, aout);
    // proj: split-K=2 (2x512), atomic combine into resid
    gl<M_RESID>(stream, 2048, 1024, 512, aout, 1024, wproj, 1024, 0,
                nullptr, proj_b + l * 1024, xbuf,
                nullptr, nullptr, nullptr, 512, 512, 2);

    // ---- ffn block ----
    ln_kernel<<<2048, 256, 0, stream>>>(xbuf, ln2_g + l * 1024, ln2_b + l * 1024, hbuf);
    gl<M_FC1>(stream, 2048, 4096, 1024, hbuf, 1024, wfc1, 1024, 4096,
              abuf, fc1_b + l * 4096, nullptr);
    // fc2: split-K=4 (4x1024), atomic combine into resid
    gl<M_RESID>(stream, 2048, 1024, 1024, abuf, 4096, wfc2, 4096, 0,
                nullptr, fc2_b + l * 1024, xbuf,
                nullptr, nullptr, nullptr, 1024, 1024, 4);
  }
}

// Round 8
// 1070.508 us; speedup vs baseline: 1.1268x; 1.0330x over previous
//
#include <hip/hip_runtime.h>
#include <cstdint>
#include <cstddef>

// CP_TransformerDecoder on MI355X — round 8: occupancy-first GEMM.
// Round-7 counters: MfmaUtil 11%, occupancy 13.7% — grid (512 WGs) and 64KB
// dbuf LDS cap residency at 2 blocks/CU; 1-step prefetch can't cover HBM
// latency at 2 waves/SIMD. Revert to single-buffer 2-barrier loop (m97) with
// 64x128 tile (24 KB LDS -> up to 6 blocks/CU), __launch_bounds__(256,4),
// grids >= 1024 WGs (fc2/proj splitK=4, fc1 32x32, qkv 32x24).

typedef __bf16 bf16_t;
typedef __bf16 bf16x8 __attribute__((ext_vector_type(8)));
typedef float  f32x4  __attribute__((ext_vector_type(4)));

#define DEVI __device__ __forceinline__

DEVI f32x4 mfma16(bf16x8 a, bf16x8 b, f32x4 c) {
  return __builtin_amdgcn_mfma_f32_16x16x32_bf16(a, b, c, 0, 0, 0);
}

DEVI void async16(const void* g, void* l) {
  __builtin_amdgcn_global_load_lds((const __attribute__((address_space(1))) void*)g,
                                   (__attribute__((address_space(3))) void*)l, 16, 0, 0);
}

DEVI float gelu_f(float v) { return 0.5f * v * (1.0f + erff(v * 0.70710678118654752440f)); }

// ---------------- preprocessing ----------------

// u_wT[c][r] = u_w[r][c]  (bf16), LDS-tiled transpose
__global__ __launch_bounds__(256) void utrans_kernel(const float* __restrict__ u_w,
                                                     bf16_t* __restrict__ out) {
  __shared__ float T[64][65];
  int t = threadIdx.x, c0 = blockIdx.x * 64;
#pragma unroll
  for (int i = 0; i < 16; ++i) {
    int idx = i * 256 + t;
    int r = idx >> 6, c = idx & 63;
    T[r][c] = u_w[r * 1024 + c0 + c];
  }
  __syncthreads();
#pragma unroll
  for (int i = 0; i < 16; ++i) {
    int idx = i * 256 + t;
    int c = idx >> 6, r = idx & 63;
    out[(size_t)(c0 + c) * 64 + r] = (bf16_t)T[r][c];
  }
}

// CPcat[l][r1][r2][f], f=0..3 from cp_att, f=4..11 from mlp_cp
__global__ __launch_bounds__(256) void cpcat_kernel(const float* __restrict__ cp_c,
    const float* __restrict__ cp_att, const float* __restrict__ mlp_cp, float* __restrict__ cpcat) {
  int idx = blockIdx.x * 256 + threadIdx.x;  // 16384 = L*64*64
  int lay = idx >> 12, ab = idx & 4095;
  const float* crow = cp_c + (size_t)ab * 64;
  float acc[12];
#pragma unroll
  for (int f = 0; f < 12; ++f) acc[f] = 0.f;
  for (int r = 0; r < 64; ++r) {
    float cv = crow[r];
    const float* wa = cp_att + lay * 256 + r * 4;
    const float* wm = mlp_cp + lay * 512 + r * 8;
#pragma unroll
    for (int f = 0; f < 4; ++f) acc[f] += cv * wa[f];
#pragma unroll
    for (int f = 0; f < 8; ++f) acc[4 + f] += cv * wm[f];
  }
  float* o = cpcat + (size_t)idx * 12;
#pragma unroll
  for (int f = 0; f < 12; ++f) o[f] = acc[f];
}

// wpatt[l][f][cout][r1] = sum_r2 CPcat[l][r1][r2][f] * v_w[cout][r2]
__global__ __launch_bounds__(256) void wp_att_kernel(const float* __restrict__ cpcat,
    const float* __restrict__ v_w, bf16_t* __restrict__ out) {
  __shared__ float ST[64][65];
  int lay = blockIdx.y;
  int f = blockIdx.x >> 3, cc = blockIdx.x & 7;
  int t = threadIdx.x;
#pragma unroll
  for (int i = 0; i < 16; ++i) {
    int idx = i * 256 + t;
    int r1 = idx >> 6, r2 = idx & 63;
    ST[r2][r1] = cpcat[(size_t)(lay * 4096 + r1 * 64 + r2) * 12 + f];
  }
  __syncthreads();
  int lane = t & 63, grp = t >> 6;
  for (int ii = 0; ii < 32; ii += 4) {
    int cb = cc * 128 + grp * 32 + ii;
    const float* v0 = v_w + (size_t)cb * 64;
    const float* v1 = v0 + 64;
    const float* v2 = v0 + 128;
    const float* v3 = v0 + 192;
    float a0 = 0.f, a1 = 0.f, a2 = 0.f, a3 = 0.f;
#pragma unroll 8
    for (int r2 = 0; r2 < 64; ++r2) {
      float sv = ST[r2][lane];
      a0 += sv * v0[r2]; a1 += sv * v1[r2]; a2 += sv * v2[r2]; a3 += sv * v3[r2];
    }
    size_t ob = ((size_t)(lay * 4 + f) * 1024 + cb) * 64 + lane;
    out[ob] = (bf16_t)a0; out[ob + 64] = (bf16_t)a1;
    out[ob + 128] = (bf16_t)a2; out[ob + 192] = (bf16_t)a3;
  }
}

// wpfc1[l][g*1024+cout][r1] = sum_rr CPcat[l][r1][g*16+(rr>>2)][4+(rr&3)] * v_w[cout][rr]
__global__ __launch_bounds__(256) void wp_fc1_kernel(const float* __restrict__ cpcat,
    const float* __restrict__ v_w, bf16_t* __restrict__ out) {
  __shared__ float ST[64][65];
  int lay = blockIdx.y;
  int g = blockIdx.x >> 3, cc = blockIdx.x & 7;
  int t = threadIdx.x;
#pragma unroll
  for (int i = 0; i < 16; ++i) {
    int idx = i * 256 + t;
    int r1 = idx >> 6, rr = idx & 63;
    ST[rr][r1] = cpcat[(size_t)(lay * 4096 + r1 * 64 + g * 16 + (rr >> 2)) * 12 + 4 + (rr & 3)];
  }
  __syncthreads();
  int lane = t & 63, grp = t >> 6;
  for (int ii = 0; ii < 32; ii += 4) {
    int cb = cc * 128 + grp * 32 + ii;
    const float* v0 = v_w + (size_t)cb * 64;
    const float* v1 = v0 + 64;
    const float* v2 = v0 + 128;
    const float* v3 = v0 + 192;
    float a0 = 0.f, a1 = 0.f, a2 = 0.f, a3 = 0.f;
#pragma unroll 8
    for (int rr = 0; rr < 64; ++rr) {
      float sv = ST[rr][lane];
      a0 += sv * v0[rr]; a1 += sv * v1[rr]; a2 += sv * v2[rr]; a3 += sv * v3[rr];
    }
    size_t ob = ((size_t)lay * 4096 + g * 1024 + cb) * 64 + lane;
    out[ob] = (bf16_t)a0; out[ob + 64] = (bf16_t)a1;
    out[ob + 128] = (bf16_t)a2; out[ob + 192] = (bf16_t)a3;
  }
}

// wpfc2[l][cout][jj] = sum_q CPcat[l][q][jj>>2][8+(jj&3)] * v_w[cout][q]
__global__ __launch_bounds__(256) void wp_fc2_kernel(const float* __restrict__ cpcat,
    const float* __restrict__ v_w, bf16_t* __restrict__ out) {
  __shared__ float SJ[64][65];
  int lay = blockIdx.y;
  int jc = blockIdx.x >> 3, cc = blockIdx.x & 7;
  int t = threadIdx.x;
#pragma unroll
  for (int i = 0; i < 16; ++i) {
    int idx = i * 256 + t;
    int q = idx >> 6, j64 = idx & 63;
    SJ[q][j64] = cpcat[(size_t)(lay * 4096 + q * 64 + jc * 16 + (j64 >> 2)) * 12 + 8 + (j64 & 3)];
  }
  __syncthreads();
  int lane = t & 63, grp = t >> 6;
  for (int ii = 0; ii < 32; ii += 4) {
    int cb = cc * 128 + grp * 32 + ii;
    const float* v0 = v_w + (size_t)cb * 64;
    const float* v1 = v0 + 64;
    const float* v2 = v0 + 128;
    const float* v3 = v0 + 192;
    float a0 = 0.f, a1 = 0.f, a2 = 0.f, a3 = 0.f;
#pragma unroll 8
    for (int q = 0; q < 64; ++q) {
      float sv = SJ[q][lane];
      a0 += sv * v0[q]; a1 += sv * v1[q]; a2 += sv * v2[q]; a3 += sv * v3[q];
    }
    size_t ob = ((size_t)lay * 1024 + cb) * 256 + jc * 64 + lane;
    out[ob] = (bf16_t)a0; out[ob + 256] = (bf16_t)a1;
    out[ob + 512] = (bf16_t)a2; out[ob + 768] = (bf16_t)a3;
  }
}

// LayerNorm over C=1024, write bf16
__global__ __launch_bounds__(256) void ln_kernel(const float* __restrict__ x,
    const float* __restrict__ g, const float* __restrict__ b, bf16_t* __restrict__ out) {
  int row = blockIdx.x;
  int t = threadIdx.x;
  const float4 v = ((const float4*)(x + (size_t)row * 1024))[t];
  float s = v.x + v.y + v.z + v.w;
  float s2 = v.x * v.x + v.y * v.y + v.z * v.z + v.w * v.w;
#pragma unroll
  for (int off = 32; off > 0; off >>= 1) {
    s += __shfl_down(s, off, 64);
    s2 += __shfl_down(s2, off, 64);
  }
  __shared__ float red[8];
  int wv = t >> 6;
  if ((t & 63) == 0) { red[wv * 2] = s; red[wv * 2 + 1] = s2; }
  __syncthreads();
  s = red[0] + red[2] + red[4] + red[6];
  s2 = red[1] + red[3] + red[5] + red[7];
  float mean = s * (1.0f / 1024.0f);
  float var = s2 * (1.0f / 1024.0f) - mean * mean;
  float rstd = rsqrtf(var + 1e-5f);
  const float4 gg = ((const float4*)g)[t];
  const float4 bb = ((const float4*)b)[t];
  union { bf16_t o[4]; uint2 u; } pk;
  pk.o[0] = (bf16_t)((v.x - mean) * rstd * gg.x + bb.x);
  pk.o[1] = (bf16_t)((v.y - mean) * rstd * gg.y + bb.y);
  pk.o[2] = (bf16_t)((v.z - mean) * rstd * gg.z + bb.z);
  pk.o[3] = (bf16_t)((v.w - mean) * rstd * gg.w + bb.w);
  *(uint2*)(out + (size_t)row * 1024 + t * 4) = pk.u;
}

// ---------------- batched weight-fold: W_eff = W + u_w^T @ P ----------------
// One dispatch per layer, virtual-tile decode over {qkv(24), proj(8), fc1(32),
// fc2(8x4z)} m-tiles x 8 n-tiles. K=64 single step. 128x128 tile.

struct PrepArgs {
  const bf16_t* uwT;
  const bf16_t* wpatt;  // layer base [4][1024][64]; proj slice at +196608
  const bf16_t* wpfc1;  // [4096][64]
  const bf16_t* wpfc2;  // [1024][256]
  const float* qkvw; const float* projw; const float* fc1w; const float* fc2w;
  bf16_t* wqkv; bf16_t* wproj; bf16_t* wfc1; bf16_t* wfc2;
};

__global__ __launch_bounds__(256, 2)
void prep_all_kernel(PrepArgs a) {
  __shared__ __align__(16) bf16_t Al[128 * 64];
  __shared__ __align__(16) bf16_t Bl[128 * 64];
  int mi = blockIdx.x, n0 = blockIdx.y * 128;
  const bf16_t* A; const float* wadd; bf16_t* outp;
  int m0, ldo = 1024, lda = 64, zcol = 0;
  if (mi < 24)      { A = a.wpatt;          m0 = mi * 128;        wadd = a.qkvw; outp = a.wqkv; }
  else if (mi < 32) { A = a.wpatt + 196608; m0 = (mi - 24) * 128; wadd = a.projw; outp = a.wproj; }
  else if (mi < 64) { A = a.wpfc1;          m0 = (mi - 32) * 128; wadd = a.fc1w; outp = a.wfc1; }
  else {
    int q = mi - 64, z = q >> 3;
    A = a.wpfc2 + z * 64; m0 = (q & 7) * 128; wadd = a.fc2w; outp = a.wfc2;
    ldo = 4096; lda = 256; zcol = z * 1024;
  }
  int tid = threadIdx.x;
  int w = tid >> 6, l = tid & 63;
  int lr = l & 15, lh = l >> 4;
  int wr = w >> 1, wc = w & 1;
  int srow = l >> 3;
  int scol = ((l & 7) << 4) ^ (srow << 4);
#pragma unroll
  for (int c = 0; c < 8; ++c) {
    int chunk = w * 8 + c;
    if (chunk < 16) {
      int row = m0 + chunk * 8 + srow;
      async16((const char*)(A + (size_t)row * lda) + scol, (char*)Al + chunk * 1024);
    } else {
      int ch = chunk - 16;
      int row = n0 + ch * 8 + srow;
      async16((const char*)(a.uwT + (size_t)row * 64) + scol, (char*)Bl + ch * 1024);
    }
  }
  __syncthreads();
  f32x4 acc[4][4];
  const f32x4 fz = {0.f, 0.f, 0.f, 0.f};
#pragma unroll
  for (int i = 0; i < 4; ++i)
#pragma unroll
    for (int j = 0; j < 4; ++j) acc[i][j] = fz;
#pragma unroll
  for (int kk = 0; kk < 2; ++kk) {
    bf16x8 af[4], bfv[4];
#pragma unroll
    for (int i = 0; i < 4; ++i) {
      int ar = wr * 64 + i * 16 + lr;
      af[i] = *(const bf16x8*)((const char*)Al + ar * 128 + (((lh << 4) + (kk << 6)) ^ ((ar & 7) << 4)));
      int br = wc * 64 + i * 16 + lr;
      bfv[i] = *(const bf16x8*)((const char*)Bl + br * 128 + (((lh << 4) + (kk << 6)) ^ ((br & 7) << 4)));
    }
#pragma unroll
    for (int i = 0; i < 4; ++i)
#pragma unroll
      for (int j = 0; j < 4; ++j) acc[i][j] = mfma16(af[i], bfv[j], acc[i][j]);
  }
#pragma unroll
  for (int i = 0; i < 4; ++i) {
    int row0 = m0 + wr * 64 + i * 16 + lh * 4;
#pragma unroll
    for (int j = 0; j < 4; ++j) {
      int colw = n0 + wc * 64 + j * 16 + lr + zcol;
#pragma unroll
      for (int r = 0; r < 4; ++r) {
        int rr = row0 + r;
        float v = acc[i][j][r] + wadd[(size_t)rr * ldo + colw];
        outp[(size_t)rr * ldo + colw] = (bf16_t)v;
      }
    }
  }
}

// ---------------- generic bf16 GEMM: C = A[M,K] @ W[N,K]^T ----------------
// 64x128 tile, BK=64, 4 waves (each 32x64), 24 KB LDS single-buffer, 2-barrier
// m97 loop, global_load_lds(16B), XOR-swizzled LDS. launch_bounds(256,4):
// high occupancy (4+ blocks/CU) is the latency-hiding mechanism (m114/m132).
// M_QKV  : scatter to q/k/v [B,H,N,D], q pre-scaled
// M_RESID: split-K partial -> atomicAdd into f32 resid (+bias on z==0)
// M_FC1  : + bias, GELU, bf16 out

enum { M_QKV = 0, M_RESID = 1, M_FC1 = 2 };

template <int MODE>
__global__ __launch_bounds__(256, 4)
void gemm_bt(const bf16_t* __restrict__ A, int lda,
             const bf16_t* __restrict__ W, int ldw,
             int N, int K, int ldc,
             bf16_t* __restrict__ bout,
             const float* __restrict__ bias,
             float* __restrict__ resid,
             bf16_t* __restrict__ qout, bf16_t* __restrict__ kout, bf16_t* __restrict__ vout,
             int az, int wz) {
  __shared__ __align__(16) bf16_t Al[64 * 64];    // 8 KB
  __shared__ __align__(16) bf16_t Bl[128 * 64];   // 16 KB
  int tid = threadIdx.x;
  int w = tid >> 6, l = tid & 63;
  int lr = l & 15, lh = l >> 4;
  int wr = w >> 1, wc = w & 1;
  int m0 = blockIdx.x * 64, n0 = blockIdx.y * 128;
  int zz = blockIdx.z;
  A += (size_t)zz * az;
  W += (size_t)zz * wz;
  f32x4 acc[2][4];
  const f32x4 fz = {0.f, 0.f, 0.f, 0.f};
#pragma unroll
  for (int i = 0; i < 2; ++i)
#pragma unroll
    for (int j = 0; j < 4; ++j) acc[i][j] = fz;

  int srow = l >> 3;                          // row within 8-row chunk
  int scol = ((l & 7) << 4) ^ (srow << 4);    // pre-swizzled source byte col (T2)

  for (int k0 = 0; k0 < K; k0 += 64) {
#pragma unroll
    for (int c = 0; c < 6; ++c) {             // 24 chunks over 4 waves
      int chunk = w * 6 + c;
      if (chunk < 8) {
        int row = m0 + chunk * 8 + srow;
        async16((const char*)(A + (size_t)row * lda + k0) + scol, (char*)Al + chunk * 1024);
      } else {
        int ch = chunk - 8;
        int row = n0 + ch * 8 + srow;
        async16((const char*)(W + (size_t)row * ldw + k0) + scol, (char*)Bl + ch * 1024);
      }
    }
    __syncthreads();
#pragma unroll
    for (int kk = 0; kk < 2; ++kk) {
      bf16x8 af[2], bfv[4];
#pragma unroll
      for (int i = 0; i < 2; ++i) {
        int ar = wr * 32 + i * 16 + lr;
        af[i] = *(const bf16x8*)((const char*)Al + ar * 128 + (((lh << 4) + (kk << 6)) ^ ((ar & 7) << 4)));
      }
#pragma unroll
      for (int j = 0; j < 4; ++j) {
        int br = wc * 64 + j * 16 + lr;
        bfv[j] = *(const bf16x8*)((const char*)Bl + br * 128 + (((lh << 4) + (kk << 6)) ^ ((br & 7) << 4)));
      }
#pragma unroll
      for (int i = 0; i < 2; ++i)
#pragma unroll
        for (int j = 0; j < 4; ++j) acc[i][j] = mfma16(af[i], bfv[j], acc[i][j]);
    }
    __syncthreads();
  }

  // epilogue — C/D layout: col = lane&15, row = (lane>>4)*4 + reg  [m89]
#pragma unroll
  for (int i = 0; i < 2; ++i) {
    int row0 = m0 + wr * 32 + i * 16 + lh * 4;
#pragma unroll
    for (int j = 0; j < 4; ++j) {
      int col = n0 + wc * 64 + j * 16 + lr;
#pragma unroll
      for (int r = 0; r < 4; ++r) {
        int rr = row0 + r;
        float v = acc[i][j][r];
        if constexpr (MODE == M_QKV) {
          int which = col >> 10, crem = col & 1023;
          int hh = crem >> 6, dd = crem & 63;
          int bb = rr >> 10, nn = rr & 1023;
          size_t di = ((size_t)(bb * 16 + hh) * 1024 + nn) * 64 + dd;
          if (which == 0) qout[di] = (bf16_t)(v * 0.125f);  // q pre-scaled by D^-0.5
          else if (which == 1) kout[di] = (bf16_t)v;
          else vout[di] = (bf16_t)v;
        } else if constexpr (MODE == M_RESID) {
          if (zz == 0) v += bias[col];
          atomicAdd(&resid[(size_t)rr * 1024 + col], v);
        } else if constexpr (MODE == M_FC1) {
          v += bias[col];
          bout[(size_t)rr * ldc + col] = (bf16_t)gelu_f(v);
        }
      }
    }
  }
}

// ---------------- flash attention (causal), bf16 MFMA ----------------

__global__ __launch_bounds__(256, 2)
void attn_kernel(const bf16_t* __restrict__ qb, const bf16_t* __restrict__ kb,
                 const bf16_t* __restrict__ vb, bf16_t* __restrict__ out) {
  __shared__ __align__(16) bf16_t Kl[64 * 64];
  __shared__ __align__(16) bf16_t Vl[64 * 64];      // V transposed: [d][key]
  __shared__ __align__(16) bf16_t Pl[4][16 * 72];
  int tid = threadIdx.x;
  int w = tid >> 6, l = tid & 63;
  int lr = l & 15, lh = l >> 4;
  int bh = blockIdx.y;
  int q0 = blockIdx.x * 64;
  const size_t base = (size_t)bh * 1024 * 64;

  const bf16_t* qrow_ptr = qb + base + (size_t)(q0 + w * 16 + lr) * 64;
  bf16x8 qf0 = *(const bf16x8*)(qrow_ptr + lh * 8);
  bf16x8 qf1 = *(const bf16x8*)(qrow_ptr + 32 + lh * 8);

  f32x4 acc_o[4];
  float m_run[4], l_run[4];
  const f32x4 fz = {0.f, 0.f, 0.f, 0.f};
#pragma unroll
  for (int i = 0; i < 4; ++i) { acc_o[i] = fz; m_run[i] = -1e30f; l_run[i] = 0.f; }

  int nt = blockIdx.x + 1;
  int srow = tid >> 2, sseg = tid & 3;

  for (int t = 0; t < nt; ++t) {
    int k0 = t * 64;
    __syncthreads();
    {  // stage K tile [key][d] (swizzled) and V^T tile [d][key] (swizzled)
      const bf16_t* ksrc = kb + base + (size_t)(k0 + srow) * 64 + sseg * 16;
      uint4 v0 = *(const uint4*)(ksrc);
      uint4 v1 = *(const uint4*)(ksrc + 8);
      int c0 = sseg * 32;
      *(uint4*)((char*)Kl + srow * 128 + (c0 ^ ((srow & 7) << 4))) = v0;
      *(uint4*)((char*)Kl + srow * 128 + ((c0 + 16) ^ ((srow & 7) << 4))) = v1;
      const bf16_t* vsrc = vb + base + (size_t)(k0 + srow) * 64 + sseg * 16;
      union { uint4 u[2]; bf16_t e[16]; } tv;
      tv.u[0] = *(const uint4*)(vsrc);
      tv.u[1] = *(const uint4*)(vsrc + 8);
#pragma unroll
      for (int j = 0; j < 16; ++j) {
        int d = sseg * 16 + j;
        *(bf16_t*)((char*)Vl + d * 128 + ((srow * 2) ^ ((d & 7) << 4))) = tv.e[j];
      }
    }
    __syncthreads();

    // S = Q K^T  (16q x 64keys per wave)
    f32x4 s[4];
#pragma unroll
    for (int kg = 0; kg < 4; ++kg) {
      int krow = kg * 16 + lr;
      const char* kbase = (const char*)Kl + krow * 128;
      int sw = (krow & 7) << 4;
      bf16x8 k0f = *(const bf16x8*)(kbase + ((lh * 16) ^ sw));
      bf16x8 k1f = *(const bf16x8*)(kbase + ((lh * 16 + 64) ^ sw));
      f32x4 z = fz;
      z = mfma16(qf0, k0f, z);
      z = mfma16(qf1, k1f, z);
      s[kg] = z;
    }

    // causal mask + online softmax (rows spread over 16-lane groups)
#pragma unroll
    for (int r = 0; r < 4; ++r) {
      int qrow = q0 + w * 16 + lh * 4 + r;
#pragma unroll
      for (int kg = 0; kg < 4; ++kg) {
        int key = k0 + kg * 16 + lr;
        if (key > qrow) s[kg][r] = -1e30f;
      }
      float mx = fmaxf(fmaxf(s[0][r], s[1][r]), fmaxf(s[2][r], s[3][r]));
      mx = fmaxf(mx, __shfl_xor(mx, 1, 64));
      mx = fmaxf(mx, __shfl_xor(mx, 2, 64));
      mx = fmaxf(mx, __shfl_xor(mx, 4, 64));
      mx = fmaxf(mx, __shfl_xor(mx, 8, 64));
      float mn = fmaxf(m_run[r], mx);
      float al = __expf(m_run[r] - mn);
      m_run[r] = mn;
      float sum = 0.f;
#pragma unroll
      for (int kg = 0; kg < 4; ++kg) {
        float pv = __expf(s[kg][r] - mn);
        s[kg][r] = pv;
        sum += pv;
      }
      sum += __shfl_xor(sum, 1, 64);
      sum += __shfl_xor(sum, 2, 64);
      sum += __shfl_xor(sum, 4, 64);
      sum += __shfl_xor(sum, 8, 64);
      l_run[r] = l_run[r] * al + sum;
#pragma unroll
      for (int dg = 0; dg < 4; ++dg) acc_o[dg][r] *= al;
#pragma unroll
      for (int kg = 0; kg < 4; ++kg)
        Pl[w][(lh * 4 + r) * 72 + kg * 16 + lr] = (bf16_t)s[kg][r];
    }

    // barrier: P rows are read by different lanes than wrote them
    __syncthreads();

    // O += P V
#pragma unroll
    for (int dg = 0; dg < 4; ++dg) {
      int vrow = dg * 16 + lr;
      const char* vbase = (const char*)Vl + vrow * 128;
      int sw = (vrow & 7) << 4;
#pragma unroll
      for (int kb2 = 0; kb2 < 2; ++kb2) {
        bf16x8 pf = *(const bf16x8*)(&Pl[w][lr * 72 + lh * 8 + kb2 * 32]);
        bf16x8 vf = *(const bf16x8*)(vbase + ((lh * 16 + kb2 * 64) ^ sw));
        acc_o[dg] = mfma16(pf, vf, acc_o[dg]);
      }
    }
  }

  int b = bh >> 4, h = bh & 15;
#pragma unroll
  for (int dg = 0; dg < 4; ++dg) {
    int col = h * 64 + dg * 16 + lr;
#pragma unroll
    for (int r = 0; r < 4; ++r) {
      int n = q0 + w * 16 + lh * 4 + r;
      out[((size_t)b * 1024 + n) * 1024 + col] = (bf16_t)(acc_o[dg][r] / l_run[r]);
    }
  }
}

// ---------------- host ----------------

template <int MODE>
static inline void gl(hipStream_t st, int M, int N, int K,
                     const bf16_t* A, int lda, const bf16_t* W, int ldw, int ldc,
                     bf16_t* bout, const float* bias, float* resid,
                     bf16_t* qo = nullptr, bf16_t* ko = nullptr, bf16_t* vo = nullptr,
                     int az = 0, int wz = 0, int gz = 1) {
  gemm_bt<MODE><<<dim3(M / 64, N / 128, gz), 256, 0, st>>>(
      A, lda, W, ldw, N, K, ldc, bout, bias, resid, qo, ko, vo, az, wz);
}

extern "C" void kernel_launch(void* const* d_in, const int* in_sizes, int n_in,
                              void* d_out, int out_size, void* d_ws, size_t ws_size,
                              hipStream_t stream) {
  const float* x_in   = (const float*)d_in[0];
  const float* ln1_g  = (const float*)d_in[2];
  const float* ln1_b  = (const float*)d_in[3];
  const float* qkv_w  = (const float*)d_in[4];
  const float* proj_w = (const float*)d_in[5];
  const float* proj_b = (const float*)d_in[6];
  const float* cp_att = (const float*)d_in[7];
  const float* ln2_g  = (const float*)d_in[8];
  const float* ln2_b  = (const float*)d_in[9];
  const float* fc1_w  = (const float*)d_in[10];
  const float* fc1_b  = (const float*)d_in[11];
  const float* fc2_w  = (const float*)d_in[12];
  const float* fc2_b  = (const float*)d_in[13];
  const float* mlp_cp = (const float*)d_in[14];
  const float* u_w    = (const float*)d_in[15];
  const float* v_w    = (const float*)d_in[16];
  const float* cp_c   = (const float*)d_in[17];
  float* xbuf = (float*)d_out;  // running residual stream

  char* p = (char*)d_ws;
  auto carve = [&](size_t bytes) { char* r = p; p += (bytes + 255) & ~(size_t)255; return r; };
  bf16_t* wl    = (bf16_t*)carve(12582912ull * 2);  // per-layer folded bf16 weights
  bf16_t* uwT   = (bf16_t*)carve(65536ull * 2);     // u_w^T [1024][64]
  float*  cpcat = (float*) carve(196608ull * 4);
  bf16_t* wpatt = (bf16_t*)carve(1048576ull * 2);   // [L][4][1024][64]
  bf16_t* wpfc1 = (bf16_t*)carve(1048576ull * 2);   // [L][4096][64]
  bf16_t* wpfc2 = (bf16_t*)carve(1048576ull * 2);   // [L][1024][256]
  bf16_t* hbuf  = (bf16_t*)carve(2097152ull * 2);
  bf16_t* qbuf  = (bf16_t*)carve(2097152ull * 2);
  bf16_t* kbuf  = (bf16_t*)carve(2097152ull * 2);
  bf16_t* vbuf  = (bf16_t*)carve(2097152ull * 2);
  bf16_t* aout  = (bf16_t*)carve(2097152ull * 2);
  bf16_t* abuf  = (bf16_t*)carve(8388608ull * 2);

  hipMemcpyAsync(xbuf, x_in, (size_t)2048 * 1024 * 4, hipMemcpyDeviceToDevice, stream);
  utrans_kernel<<<16, 256, 0, stream>>>(u_w, uwT);
  cpcat_kernel<<<64, 256, 0, stream>>>(cp_c, cp_att, mlp_cp, cpcat);
  wp_att_kernel<<<dim3(32, 4), 256, 0, stream>>>(cpcat, v_w, wpatt);
  wp_fc1_kernel<<<dim3(32, 4), 256, 0, stream>>>(cpcat, v_w, wpfc1);
  wp_fc2_kernel<<<dim3(32, 4), 256, 0, stream>>>(cpcat, v_w, wpfc2);

  for (int l = 0; l < 4; ++l) {
    bf16_t* wqkv  = wl;
    bf16_t* wproj = wl + 3145728;
    bf16_t* wfc1  = wl + 4194304;
    bf16_t* wfc2  = wl + 8388608;

    // ---- batched weight fold (1 dispatch) ----
    PrepArgs pa;
    pa.uwT = uwT;
    pa.wpatt = wpatt + (size_t)l * 262144;
    pa.wpfc1 = wpfc1 + (size_t)l * 262144;
    pa.wpfc2 = wpfc2 + (size_t)l * 262144;
    pa.qkvw = qkv_w + (size_t)l * 3145728;
    pa.projw = proj_w + (size_t)l * 1048576;
    pa.fc1w = fc1_w + (size_t)l * 4194304;
    pa.fc2w = fc2_w + (size_t)l * 4194304;
    pa.wqkv = wqkv; pa.wproj = wproj; pa.wfc1 = wfc1; pa.wfc2 = wfc2;
    prep_all_kernel<<<dim3(96, 8), 256, 0, stream>>>(pa);

    // ---- attention block ----
    ln_kernel<<<2048, 256, 0, stream>>>(xbuf, ln1_g + l * 1024, ln1_b + l * 1024, hbuf);
    gl<M_QKV>(stream, 2048, 3072, 1024, hbuf, 1024, wqkv, 1024, 0,
              nullptr, nullptr, nullptr, qbuf, kbuf, vbuf);      // 32x24 = 768 WGs
    attn_kernel<<<dim3(16, 32), 256, 0, stream>>>(qbuf, kbuf, vbuf, aout);
    // proj: split-K=4 (4x256), atomic combine into resid -> 1024 WGs
    gl<M_RESID>(stream, 2048, 1024, 256, aout, 1024, wproj, 1024, 0,
                nullptr, proj_b + l * 1024, xbuf,
                nullptr, nullptr, nullptr, 256, 256, 4);

    // ---- ffn block ----
    ln_kernel<<<2048, 256, 0, stream>>>(xbuf, ln2_g + l * 1024, ln2_b + l * 1024, hbuf);
    gl<M_FC1>(stream, 2048, 4096, 1024, hbuf, 1024, wfc1, 1024, 4096,
              abuf, fc1_b + l * 4096, nullptr);                  // 32x32 = 1024 WGs
    // fc2: split-K=4 (4x1024), atomic combine into resid -> 1024 WGs
    gl<M_RESID>(stream, 2048, 1024, 1024, abuf, 4096, wfc2, 4096, 0,
                nullptr, fc2_b + l * 1024, xbuf,
                nullptr, nullptr, nullptr, 1024, 1024, 4);
  }
}

// Round 9
// 1058.059 us; speedup vs baseline: 1.1400x; 1.0118x over previous
//
#include <hip/hip_runtime.h>
#include <cstdint>
#include <cstddef>

// CP_TransformerDecoder on MI355X — round 9: attention split-KV + XCD swizzle.
// Round-8 counters: attn = new top class (52us, MfmaUtil 2.9%, occ 10%,
// triangular tail imbalance). Redesign: 8 waves/block, even/odd KV-tile teams
// with private online-softmax state, exact merge via LDS; reversed q-tile
// order. GEMMs get T1 bijective XCD swizzle (grids all %8==0).

typedef __bf16 bf16_t;
typedef __bf16 bf16x8 __attribute__((ext_vector_type(8)));
typedef float  f32x4  __attribute__((ext_vector_type(4)));

#define DEVI __device__ __forceinline__

DEVI f32x4 mfma16(bf16x8 a, bf16x8 b, f32x4 c) {
  return __builtin_amdgcn_mfma_f32_16x16x32_bf16(a, b, c, 0, 0, 0);
}

DEVI void async16(const void* g, void* l) {
  __builtin_amdgcn_global_load_lds((const __attribute__((address_space(1))) void*)g,
                                   (__attribute__((address_space(3))) void*)l, 16, 0, 0);
}

DEVI float gelu_f(float v) { return 0.5f * v * (1.0f + erff(v * 0.70710678118654752440f)); }

// ---------------- preprocessing ----------------

// u_wT[c][r] = u_w[r][c]  (bf16), LDS-tiled transpose
__global__ __launch_bounds__(256) void utrans_kernel(const float* __restrict__ u_w,
                                                     bf16_t* __restrict__ out) {
  __shared__ float T[64][65];
  int t = threadIdx.x, c0 = blockIdx.x * 64;
#pragma unroll
  for (int i = 0; i < 16; ++i) {
    int idx = i * 256 + t;
    int r = idx >> 6, c = idx & 63;
    T[r][c] = u_w[r * 1024 + c0 + c];
  }
  __syncthreads();
#pragma unroll
  for (int i = 0; i < 16; ++i) {
    int idx = i * 256 + t;
    int c = idx >> 6, r = idx & 63;
    out[(size_t)(c0 + c) * 64 + r] = (bf16_t)T[r][c];
  }
}

// CPcat[l][r1][r2][f], f=0..3 from cp_att, f=4..11 from mlp_cp
__global__ __launch_bounds__(256) void cpcat_kernel(const float* __restrict__ cp_c,
    const float* __restrict__ cp_att, const float* __restrict__ mlp_cp, float* __restrict__ cpcat) {
  int idx = blockIdx.x * 256 + threadIdx.x;  // 16384 = L*64*64
  int lay = idx >> 12, ab = idx & 4095;
  const float* crow = cp_c + (size_t)ab * 64;
  float acc[12];
#pragma unroll
  for (int f = 0; f < 12; ++f) acc[f] = 0.f;
  for (int r = 0; r < 64; ++r) {
    float cv = crow[r];
    const float* wa = cp_att + lay * 256 + r * 4;
    const float* wm = mlp_cp + lay * 512 + r * 8;
#pragma unroll
    for (int f = 0; f < 4; ++f) acc[f] += cv * wa[f];
#pragma unroll
    for (int f = 0; f < 8; ++f) acc[4 + f] += cv * wm[f];
  }
  float* o = cpcat + (size_t)idx * 12;
#pragma unroll
  for (int f = 0; f < 12; ++f) o[f] = acc[f];
}

// wpatt[l][f][cout][r1] = sum_r2 CPcat[l][r1][r2][f] * v_w[cout][r2]
__global__ __launch_bounds__(256) void wp_att_kernel(const float* __restrict__ cpcat,
    const float* __restrict__ v_w, bf16_t* __restrict__ out) {
  __shared__ float ST[64][65];
  int lay = blockIdx.y;
  int f = blockIdx.x >> 3, cc = blockIdx.x & 7;
  int t = threadIdx.x;
#pragma unroll
  for (int i = 0; i < 16; ++i) {
    int idx = i * 256 + t;
    int r1 = idx >> 6, r2 = idx & 63;
    ST[r2][r1] = cpcat[(size_t)(lay * 4096 + r1 * 64 + r2) * 12 + f];
  }
  __syncthreads();
  int lane = t & 63, grp = t >> 6;
  for (int ii = 0; ii < 32; ii += 4) {
    int cb = cc * 128 + grp * 32 + ii;
    const float* v0 = v_w + (size_t)cb * 64;
    const float* v1 = v0 + 64;
    const float* v2 = v0 + 128;
    const float* v3 = v0 + 192;
    float a0 = 0.f, a1 = 0.f, a2 = 0.f, a3 = 0.f;
#pragma unroll 8
    for (int r2 = 0; r2 < 64; ++r2) {
      float sv = ST[r2][lane];
      a0 += sv * v0[r2]; a1 += sv * v1[r2]; a2 += sv * v2[r2]; a3 += sv * v3[r2];
    }
    size_t ob = ((size_t)(lay * 4 + f) * 1024 + cb) * 64 + lane;
    out[ob] = (bf16_t)a0; out[ob + 64] = (bf16_t)a1;
    out[ob + 128] = (bf16_t)a2; out[ob + 192] = (bf16_t)a3;
  }
}

// wpfc1[l][g*1024+cout][r1] = sum_rr CPcat[l][r1][g*16+(rr>>2)][4+(rr&3)] * v_w[cout][rr]
__global__ __launch_bounds__(256) void wp_fc1_kernel(const float* __restrict__ cpcat,
    const float* __restrict__ v_w, bf16_t* __restrict__ out) {
  __shared__ float ST[64][65];
  int lay = blockIdx.y;
  int g = blockIdx.x >> 3, cc = blockIdx.x & 7;
  int t = threadIdx.x;
#pragma unroll
  for (int i = 0; i < 16; ++i) {
    int idx = i * 256 + t;
    int r1 = idx >> 6, rr = idx & 63;
    ST[rr][r1] = cpcat[(size_t)(lay * 4096 + r1 * 64 + g * 16 + (rr >> 2)) * 12 + 4 + (rr & 3)];
  }
  __syncthreads();
  int lane = t & 63, grp = t >> 6;
  for (int ii = 0; ii < 32; ii += 4) {
    int cb = cc * 128 + grp * 32 + ii;
    const float* v0 = v_w + (size_t)cb * 64;
    const float* v1 = v0 + 64;
    const float* v2 = v0 + 128;
    const float* v3 = v0 + 192;
    float a0 = 0.f, a1 = 0.f, a2 = 0.f, a3 = 0.f;
#pragma unroll 8
    for (int rr = 0; rr < 64; ++rr) {
      float sv = ST[rr][lane];
      a0 += sv * v0[rr]; a1 += sv * v1[rr]; a2 += sv * v2[rr]; a3 += sv * v3[rr];
    }
    size_t ob = ((size_t)lay * 4096 + g * 1024 + cb) * 64 + lane;
    out[ob] = (bf16_t)a0; out[ob + 64] = (bf16_t)a1;
    out[ob + 128] = (bf16_t)a2; out[ob + 192] = (bf16_t)a3;
  }
}

// wpfc2[l][cout][jj] = sum_q CPcat[l][q][jj>>2][8+(jj&3)] * v_w[cout][q]
__global__ __launch_bounds__(256) void wp_fc2_kernel(const float* __restrict__ cpcat,
    const float* __restrict__ v_w, bf16_t* __restrict__ out) {
  __shared__ float SJ[64][65];
  int lay = blockIdx.y;
  int jc = blockIdx.x >> 3, cc = blockIdx.x & 7;
  int t = threadIdx.x;
#pragma unroll
  for (int i = 0; i < 16; ++i) {
    int idx = i * 256 + t;
    int q = idx >> 6, j64 = idx & 63;
    SJ[q][j64] = cpcat[(size_t)(lay * 4096 + q * 64 + jc * 16 + (j64 >> 2)) * 12 + 8 + (j64 & 3)];
  }
  __syncthreads();
  int lane = t & 63, grp = t >> 6;
  for (int ii = 0; ii < 32; ii += 4) {
    int cb = cc * 128 + grp * 32 + ii;
    const float* v0 = v_w + (size_t)cb * 64;
    const float* v1 = v0 + 64;
    const float* v2 = v0 + 128;
    const float* v3 = v0 + 192;
    float a0 = 0.f, a1 = 0.f, a2 = 0.f, a3 = 0.f;
#pragma unroll 8
    for (int q = 0; q < 64; ++q) {
      float sv = SJ[q][lane];
      a0 += sv * v0[q]; a1 += sv * v1[q]; a2 += sv * v2[q]; a3 += sv * v3[q];
    }
    size_t ob = ((size_t)lay * 1024 + cb) * 256 + jc * 64 + lane;
    out[ob] = (bf16_t)a0; out[ob + 256] = (bf16_t)a1;
    out[ob + 512] = (bf16_t)a2; out[ob + 768] = (bf16_t)a3;
  }
}

// LayerNorm over C=1024, write bf16
__global__ __launch_bounds__(256) void ln_kernel(const float* __restrict__ x,
    const float* __restrict__ g, const float* __restrict__ b, bf16_t* __restrict__ out) {
  int row = blockIdx.x;
  int t = threadIdx.x;
  const float4 v = ((const float4*)(x + (size_t)row * 1024))[t];
  float s = v.x + v.y + v.z + v.w;
  float s2 = v.x * v.x + v.y * v.y + v.z * v.z + v.w * v.w;
#pragma unroll
  for (int off = 32; off > 0; off >>= 1) {
    s += __shfl_down(s, off, 64);
    s2 += __shfl_down(s2, off, 64);
  }
  __shared__ float red[8];
  int wv = t >> 6;
  if ((t & 63) == 0) { red[wv * 2] = s; red[wv * 2 + 1] = s2; }
  __syncthreads();
  s = red[0] + red[2] + red[4] + red[6];
  s2 = red[1] + red[3] + red[5] + red[7];
  float mean = s * (1.0f / 1024.0f);
  float var = s2 * (1.0f / 1024.0f) - mean * mean;
  float rstd = rsqrtf(var + 1e-5f);
  const float4 gg = ((const float4*)g)[t];
  const float4 bb = ((const float4*)b)[t];
  union { bf16_t o[4]; uint2 u; } pk;
  pk.o[0] = (bf16_t)((v.x - mean) * rstd * gg.x + bb.x);
  pk.o[1] = (bf16_t)((v.y - mean) * rstd * gg.y + bb.y);
  pk.o[2] = (bf16_t)((v.z - mean) * rstd * gg.z + bb.z);
  pk.o[3] = (bf16_t)((v.w - mean) * rstd * gg.w + bb.w);
  *(uint2*)(out + (size_t)row * 1024 + t * 4) = pk.u;
}

// ---------------- batched weight-fold: W_eff = W + u_w^T @ P ----------------

struct PrepArgs {
  const bf16_t* uwT;
  const bf16_t* wpatt;  // layer base [4][1024][64]; proj slice at +196608
  const bf16_t* wpfc1;  // [4096][64]
  const bf16_t* wpfc2;  // [1024][256]
  const float* qkvw; const float* projw; const float* fc1w; const float* fc2w;
  bf16_t* wqkv; bf16_t* wproj; bf16_t* wfc1; bf16_t* wfc2;
};

__global__ __launch_bounds__(256, 2)
void prep_all_kernel(PrepArgs a) {
  __shared__ __align__(16) bf16_t Al[128 * 64];
  __shared__ __align__(16) bf16_t Bl[128 * 64];
  int mi = blockIdx.x, n0 = blockIdx.y * 128;
  const bf16_t* A; const float* wadd; bf16_t* outp;
  int m0, ldo = 1024, lda = 64, zcol = 0;
  if (mi < 24)      { A = a.wpatt;          m0 = mi * 128;        wadd = a.qkvw; outp = a.wqkv; }
  else if (mi < 32) { A = a.wpatt + 196608; m0 = (mi - 24) * 128; wadd = a.projw; outp = a.wproj; }
  else if (mi < 64) { A = a.wpfc1;          m0 = (mi - 32) * 128; wadd = a.fc1w; outp = a.wfc1; }
  else {
    int q = mi - 64, z = q >> 3;
    A = a.wpfc2 + z * 64; m0 = (q & 7) * 128; wadd = a.fc2w; outp = a.wfc2;
    ldo = 4096; lda = 256; zcol = z * 1024;
  }
  int tid = threadIdx.x;
  int w = tid >> 6, l = tid & 63;
  int lr = l & 15, lh = l >> 4;
  int wr = w >> 1, wc = w & 1;
  int srow = l >> 3;
  int scol = ((l & 7) << 4) ^ (srow << 4);
#pragma unroll
  for (int c = 0; c < 8; ++c) {
    int chunk = w * 8 + c;
    if (chunk < 16) {
      int row = m0 + chunk * 8 + srow;
      async16((const char*)(A + (size_t)row * lda) + scol, (char*)Al + chunk * 1024);
    } else {
      int ch = chunk - 16;
      int row = n0 + ch * 8 + srow;
      async16((const char*)(a.uwT + (size_t)row * 64) + scol, (char*)Bl + ch * 1024);
    }
  }
  __syncthreads();
  f32x4 acc[4][4];
  const f32x4 fz = {0.f, 0.f, 0.f, 0.f};
#pragma unroll
  for (int i = 0; i < 4; ++i)
#pragma unroll
    for (int j = 0; j < 4; ++j) acc[i][j] = fz;
#pragma unroll
  for (int kk = 0; kk < 2; ++kk) {
    bf16x8 af[4], bfv[4];
#pragma unroll
    for (int i = 0; i < 4; ++i) {
      int ar = wr * 64 + i * 16 + lr;
      af[i] = *(const bf16x8*)((const char*)Al + ar * 128 + (((lh << 4) + (kk << 6)) ^ ((ar & 7) << 4)));
      int br = wc * 64 + i * 16 + lr;
      bfv[i] = *(const bf16x8*)((const char*)Bl + br * 128 + (((lh << 4) + (kk << 6)) ^ ((br & 7) << 4)));
    }
#pragma unroll
    for (int i = 0; i < 4; ++i)
#pragma unroll
      for (int j = 0; j < 4; ++j) acc[i][j] = mfma16(af[i], bfv[j], acc[i][j]);
  }
#pragma unroll
  for (int i = 0; i < 4; ++i) {
    int row0 = m0 + wr * 64 + i * 16 + lh * 4;
#pragma unroll
    for (int j = 0; j < 4; ++j) {
      int colw = n0 + wc * 64 + j * 16 + lr + zcol;
#pragma unroll
      for (int r = 0; r < 4; ++r) {
        int rr = row0 + r;
        float v = acc[i][j][r] + wadd[(size_t)rr * ldo + colw];
        outp[(size_t)rr * ldo + colw] = (bf16_t)v;
      }
    }
  }
}

// ---------------- generic bf16 GEMM: C = A[M,K] @ W[N,K]^T ----------------
// 64x128 tile, 24 KB LDS single-buffer, 2-barrier m97 loop, launch_bounds(256,4),
// T1 bijective XCD swizzle (all grids %8==0).

enum { M_QKV = 0, M_RESID = 1, M_FC1 = 2 };

template <int MODE>
__global__ __launch_bounds__(256, 4)
void gemm_bt(const bf16_t* __restrict__ A, int lda,
             const bf16_t* __restrict__ W, int ldw,
             int N, int K, int ldc,
             bf16_t* __restrict__ bout,
             const float* __restrict__ bias,
             float* __restrict__ resid,
             bf16_t* __restrict__ qout, bf16_t* __restrict__ kout, bf16_t* __restrict__ vout,
             int az, int wz) {
  __shared__ __align__(16) bf16_t Al[64 * 64];    // 8 KB
  __shared__ __align__(16) bf16_t Bl[128 * 64];   // 16 KB
  int tid = threadIdx.x;
  int w = tid >> 6, l = tid & 63;
  int lr = l & 15, lh = l >> 4;
  int wr = w >> 1, wc = w & 1;
  // T1 XCD swizzle: consecutive hardware bids round-robin XCDs; remap so each
  // XCD owns a contiguous tile range (shares W n-panels in its L2). nwg%8==0.
  int nwg = gridDim.x * gridDim.y;
  int bid = blockIdx.y * gridDim.x + blockIdx.x;
  int swz = (bid & 7) * (nwg >> 3) + (bid >> 3);
  int m0 = (swz % gridDim.x) * 64, n0 = (swz / gridDim.x) * 128;
  int zz = blockIdx.z;
  A += (size_t)zz * az;
  W += (size_t)zz * wz;
  f32x4 acc[2][4];
  const f32x4 fz = {0.f, 0.f, 0.f, 0.f};
#pragma unroll
  for (int i = 0; i < 2; ++i)
#pragma unroll
    for (int j = 0; j < 4; ++j) acc[i][j] = fz;

  int srow = l >> 3;                          // row within 8-row chunk
  int scol = ((l & 7) << 4) ^ (srow << 4);    // pre-swizzled source byte col (T2)

  for (int k0 = 0; k0 < K; k0 += 64) {
#pragma unroll
    for (int c = 0; c < 6; ++c) {             // 24 chunks over 4 waves
      int chunk = w * 6 + c;
      if (chunk < 8) {
        int row = m0 + chunk * 8 + srow;
        async16((const char*)(A + (size_t)row * lda + k0) + scol, (char*)Al + chunk * 1024);
      } else {
        int ch = chunk - 8;
        int row = n0 + ch * 8 + srow;
        async16((const char*)(W + (size_t)row * ldw + k0) + scol, (char*)Bl + ch * 1024);
      }
    }
    __syncthreads();
#pragma unroll
    for (int kk = 0; kk < 2; ++kk) {
      bf16x8 af[2], bfv[4];
#pragma unroll
      for (int i = 0; i < 2; ++i) {
        int ar = wr * 32 + i * 16 + lr;
        af[i] = *(const bf16x8*)((const char*)Al + ar * 128 + (((lh << 4) + (kk << 6)) ^ ((ar & 7) << 4)));
      }
#pragma unroll
      for (int j = 0; j < 4; ++j) {
        int br = wc * 64 + j * 16 + lr;
        bfv[j] = *(const bf16x8*)((const char*)Bl + br * 128 + (((lh << 4) + (kk << 6)) ^ ((br & 7) << 4)));
      }
#pragma unroll
      for (int i = 0; i < 2; ++i)
#pragma unroll
        for (int j = 0; j < 4; ++j) acc[i][j] = mfma16(af[i], bfv[j], acc[i][j]);
    }
    __syncthreads();
  }

  // epilogue — C/D layout: col = lane&15, row = (lane>>4)*4 + reg  [m89]
#pragma unroll
  for (int i = 0; i < 2; ++i) {
    int row0 = m0 + wr * 32 + i * 16 + lh * 4;
#pragma unroll
    for (int j = 0; j < 4; ++j) {
      int col = n0 + wc * 64 + j * 16 + lr;
#pragma unroll
      for (int r = 0; r < 4; ++r) {
        int rr = row0 + r;
        float v = acc[i][j][r];
        if constexpr (MODE == M_QKV) {
          int which = col >> 10, crem = col & 1023;
          int hh = crem >> 6, dd = crem & 63;
          int bb = rr >> 10, nn = rr & 1023;
          size_t di = ((size_t)(bb * 16 + hh) * 1024 + nn) * 64 + dd;
          if (which == 0) qout[di] = (bf16_t)(v * 0.125f);  // q pre-scaled by D^-0.5
          else if (which == 1) kout[di] = (bf16_t)v;
          else vout[di] = (bf16_t)v;
        } else if constexpr (MODE == M_RESID) {
          if (zz == 0) v += bias[col];
          atomicAdd(&resid[(size_t)rr * 1024 + col], v);
        } else if constexpr (MODE == M_FC1) {
          v += bias[col];
          bout[(size_t)rr * ldc + col] = (bf16_t)gelu_f(v);
        }
      }
    }
  }
}

// ---------------- flash attention (causal), split-KV, bf16 MFMA ----------------
// grid (16, B*H), 512 threads (8 waves). Waves 0-3 (team 0) process even KV
// tiles, waves 4-7 (team 1) odd tiles; each team keeps private online-softmax
// state for the same 64 q-rows; exact merge at the end via LDS. q-tile order
// reversed so the longest blocks launch first.

__global__ __launch_bounds__(512, 4)
void attn_kernel(const bf16_t* __restrict__ qb, const bf16_t* __restrict__ kb,
                 const bf16_t* __restrict__ vb, bf16_t* __restrict__ out) {
  __shared__ __align__(16) bf16_t Kl[2][64 * 64];
  __shared__ __align__(16) bf16_t Vl[2][64 * 64];   // V transposed: [d][key]
  __shared__ __align__(16) bf16_t Pl[8][16 * 72];
  __shared__ float mergeb[4][24][64];               // team1 (m,l,O) exchange
  int tid = threadIdx.x;
  int w = tid >> 6, l = tid & 63;
  int lr = l & 15, lh = l >> 4;
  int team = w >> 2, wr4 = w & 3;
  int bh = blockIdx.y;
  int qt = gridDim.x - 1 - blockIdx.x;  // reversed: long blocks first
  int q0 = qt * 64;
  int nt = qt + 1;
  const size_t base = (size_t)bh * 1024 * 64;

  const bf16_t* qrow_ptr = qb + base + (size_t)(q0 + wr4 * 16 + lr) * 64;
  bf16x8 qf0 = *(const bf16x8*)(qrow_ptr + lh * 8);
  bf16x8 qf1 = *(const bf16x8*)(qrow_ptr + 32 + lh * 8);

  f32x4 acc_o[4];
  float m_run[4], l_run[4];
  const f32x4 fz = {0.f, 0.f, 0.f, 0.f};
#pragma unroll
  for (int i = 0; i < 4; ++i) { acc_o[i] = fz; m_run[i] = -1e30f; l_run[i] = 0.f; }

  int ns = (nt + 1) >> 1;
  int steam = tid >> 8;          // staging team (256 threads each)
  int st = tid & 255;
  int srow = st >> 2, sseg = st & 3;

  for (int s = 0; s < ns; ++s) {
    int myt = 2 * s + team;
    __syncthreads();   // previous iteration's LDS reads complete
    {
      int stt = 2 * s + steam;
      if (stt < nt) {  // stage K tile [key][d] (swizzled) and V^T tile [d][key]
        int k0s = stt * 64;
        const bf16_t* ksrc = kb + base + (size_t)(k0s + srow) * 64 + sseg * 16;
        uint4 v0 = *(const uint4*)(ksrc);
        uint4 v1 = *(const uint4*)(ksrc + 8);
        int c0 = sseg * 32;
        *(uint4*)((char*)Kl[steam] + srow * 128 + (c0 ^ ((srow & 7) << 4))) = v0;
        *(uint4*)((char*)Kl[steam] + srow * 128 + ((c0 + 16) ^ ((srow & 7) << 4))) = v1;
        const bf16_t* vsrc = vb + base + (size_t)(k0s + srow) * 64 + sseg * 16;
        union { uint4 u[2]; bf16_t e[16]; } tv;
        tv.u[0] = *(const uint4*)(vsrc);
        tv.u[1] = *(const uint4*)(vsrc + 8);
#pragma unroll
        for (int j = 0; j < 16; ++j) {
          int d = sseg * 16 + j;
          *(bf16_t*)((char*)Vl[steam] + d * 128 + ((srow * 2) ^ ((d & 7) << 4))) = tv.e[j];
        }
      }
    }
    __syncthreads();

    bool act = myt < nt;
    int k0 = myt * 64;
    if (act) {
      // S = Q K^T  (16q x 64keys per wave)
      f32x4 s4[4];
#pragma unroll
      for (int kg = 0; kg < 4; ++kg) {
        int krow = kg * 16 + lr;
        const char* kbase = (const char*)Kl[team] + krow * 128;
        int sw = (krow & 7) << 4;
        bf16x8 k0f = *(const bf16x8*)(kbase + ((lh * 16) ^ sw));
        bf16x8 k1f = *(const bf16x8*)(kbase + ((lh * 16 + 64) ^ sw));
        f32x4 z = fz;
        z = mfma16(qf0, k0f, z);
        z = mfma16(qf1, k1f, z);
        s4[kg] = z;
      }
      // causal mask + online softmax
#pragma unroll
      for (int r = 0; r < 4; ++r) {
        int qrow = q0 + wr4 * 16 + lh * 4 + r;
#pragma unroll
        for (int kg = 0; kg < 4; ++kg) {
          int key = k0 + kg * 16 + lr;
          if (key > qrow) s4[kg][r] = -1e30f;
        }
        float mx = fmaxf(fmaxf(s4[0][r], s4[1][r]), fmaxf(s4[2][r], s4[3][r]));
        mx = fmaxf(mx, __shfl_xor(mx, 1, 64));
        mx = fmaxf(mx, __shfl_xor(mx, 2, 64));
        mx = fmaxf(mx, __shfl_xor(mx, 4, 64));
        mx = fmaxf(mx, __shfl_xor(mx, 8, 64));
        float mn = fmaxf(m_run[r], mx);
        float al = __expf(m_run[r] - mn);
        m_run[r] = mn;
        float sum = 0.f;
#pragma unroll
        for (int kg = 0; kg < 4; ++kg) {
          float pv = __expf(s4[kg][r] - mn);
          s4[kg][r] = pv;
          sum += pv;
        }
        sum += __shfl_xor(sum, 1, 64);
        sum += __shfl_xor(sum, 2, 64);
        sum += __shfl_xor(sum, 4, 64);
        sum += __shfl_xor(sum, 8, 64);
        l_run[r] = l_run[r] * al + sum;
#pragma unroll
        for (int dg = 0; dg < 4; ++dg) acc_o[dg][r] *= al;
#pragma unroll
        for (int kg = 0; kg < 4; ++kg)
          Pl[w][(lh * 4 + r) * 72 + kg * 16 + lr] = (bf16_t)s4[kg][r];
      }
    }
    __syncthreads();   // P visible to own wave's other lanes
    if (act) {
      // O += P V
#pragma unroll
      for (int dg = 0; dg < 4; ++dg) {
        int vrow = dg * 16 + lr;
        const char* vbase = (const char*)Vl[team] + vrow * 128;
        int sw = (vrow & 7) << 4;
#pragma unroll
        for (int kb2 = 0; kb2 < 2; ++kb2) {
          bf16x8 pf = *(const bf16x8*)(&Pl[w][lr * 72 + lh * 8 + kb2 * 32]);
          bf16x8 vf = *(const bf16x8*)(vbase + ((lh * 16 + kb2 * 64) ^ sw));
          acc_o[dg] = mfma16(pf, vf, acc_o[dg]);
        }
      }
    }
  }

  // ---- merge team1 into team0, write output ----
  __syncthreads();
  if (team == 1) {
#pragma unroll
    for (int r = 0; r < 4; ++r) {
      mergeb[wr4][r][l] = m_run[r];
      mergeb[wr4][4 + r][l] = l_run[r];
    }
#pragma unroll
    for (int dg = 0; dg < 4; ++dg)
#pragma unroll
      for (int r = 0; r < 4; ++r) mergeb[wr4][8 + dg * 4 + r][l] = acc_o[dg][r];
  }
  __syncthreads();
  if (team == 0) {
    int b = bh >> 4, h = bh & 15;
#pragma unroll
    for (int r = 0; r < 4; ++r) {
      float mB = mergeb[wr4][r][l];
      float lB = mergeb[wr4][4 + r][l];
      float mn = fmaxf(m_run[r], mB);
      float fA = __expf(m_run[r] - mn);
      float fB = __expf(mB - mn);
      float li = 1.0f / (l_run[r] * fA + lB * fB);
      int n = q0 + wr4 * 16 + lh * 4 + r;
#pragma unroll
      for (int dg = 0; dg < 4; ++dg) {
        float oB = mergeb[wr4][8 + dg * 4 + r][l];
        int col = h * 64 + dg * 16 + lr;
        out[((size_t)b * 1024 + n) * 1024 + col] = (bf16_t)((acc_o[dg][r] * fA + oB * fB) * li);
      }
    }
  }
}

// ---------------- host ----------------

template <int MODE>
static inline void gl(hipStream_t st, int M, int N, int K,
                     const bf16_t* A, int lda, const bf16_t* W, int ldw, int ldc,
                     bf16_t* bout, const float* bias, float* resid,
                     bf16_t* qo = nullptr, bf16_t* ko = nullptr, bf16_t* vo = nullptr,
                     int az = 0, int wz = 0, int gz = 1) {
  gemm_bt<MODE><<<dim3(M / 64, N / 128, gz), 256, 0, st>>>(
      A, lda, W, ldw, N, K, ldc, bout, bias, resid, qo, ko, vo, az, wz);
}

extern "C" void kernel_launch(void* const* d_in, const int* in_sizes, int n_in,
                              void* d_out, int out_size, void* d_ws, size_t ws_size,
                              hipStream_t stream) {
  const float* x_in   = (const float*)d_in[0];
  const float* ln1_g  = (const float*)d_in[2];
  const float* ln1_b  = (const float*)d_in[3];
  const float* qkv_w  = (const float*)d_in[4];
  const float* proj_w = (const float*)d_in[5];
  const float* proj_b = (const float*)d_in[6];
  const float* cp_att = (const float*)d_in[7];
  const float* ln2_g  = (const float*)d_in[8];
  const float* ln2_b  = (const float*)d_in[9];
  const float* fc1_w  = (const float*)d_in[10];
  const float* fc1_b  = (const float*)d_in[11];
  const float* fc2_w  = (const float*)d_in[12];
  const float* fc2_b  = (const float*)d_in[13];
  const float* mlp_cp = (const float*)d_in[14];
  const float* u_w    = (const float*)d_in[15];
  const float* v_w    = (const float*)d_in[16];
  const float* cp_c   = (const float*)d_in[17];
  float* xbuf = (float*)d_out;  // running residual stream

  char* p = (char*)d_ws;
  auto carve = [&](size_t bytes) { char* r = p; p += (bytes + 255) & ~(size_t)255; return r; };
  bf16_t* wl    = (bf16_t*)carve(12582912ull * 2);  // per-layer folded bf16 weights
  bf16_t* uwT   = (bf16_t*)carve(65536ull * 2);     // u_w^T [1024][64]
  float*  cpcat = (float*) carve(196608ull * 4);
  bf16_t* wpatt = (bf16_t*)carve(1048576ull * 2);   // [L][4][1024][64]
  bf16_t* wpfc1 = (bf16_t*)carve(1048576ull * 2);   // [L][4096][64]
  bf16_t* wpfc2 = (bf16_t*)carve(1048576ull * 2);   // [L][1024][256]
  bf16_t* hbuf  = (bf16_t*)carve(2097152ull * 2);
  bf16_t* qbuf  = (bf16_t*)carve(2097152ull * 2);
  bf16_t* kbuf  = (bf16_t*)carve(2097152ull * 2);
  bf16_t* vbuf  = (bf16_t*)carve(2097152ull * 2);
  bf16_t* aout  = (bf16_t*)carve(2097152ull * 2);
  bf16_t* abuf  = (bf16_t*)carve(8388608ull * 2);

  hipMemcpyAsync(xbuf, x_in, (size_t)2048 * 1024 * 4, hipMemcpyDeviceToDevice, stream);
  utrans_kernel<<<16, 256, 0, stream>>>(u_w, uwT);
  cpcat_kernel<<<64, 256, 0, stream>>>(cp_c, cp_att, mlp_cp, cpcat);
  wp_att_kernel<<<dim3(32, 4), 256, 0, stream>>>(cpcat, v_w, wpatt);
  wp_fc1_kernel<<<dim3(32, 4), 256, 0, stream>>>(cpcat, v_w, wpfc1);
  wp_fc2_kernel<<<dim3(32, 4), 256, 0, stream>>>(cpcat, v_w, wpfc2);

  for (int l = 0; l < 4; ++l) {
    bf16_t* wqkv  = wl;
    bf16_t* wproj = wl + 3145728;
    bf16_t* wfc1  = wl + 4194304;
    bf16_t* wfc2  = wl + 8388608;

    // ---- batched weight fold (1 dispatch) ----
    PrepArgs pa;
    pa.uwT = uwT;
    pa.wpatt = wpatt + (size_t)l * 262144;
    pa.wpfc1 = wpfc1 + (size_t)l * 262144;
    pa.wpfc2 = wpfc2 + (size_t)l * 262144;
    pa.qkvw = qkv_w + (size_t)l * 3145728;
    pa.projw = proj_w + (size_t)l * 1048576;
    pa.fc1w = fc1_w + (size_t)l * 4194304;
    pa.fc2w = fc2_w + (size_t)l * 4194304;
    pa.wqkv = wqkv; pa.wproj = wproj; pa.wfc1 = wfc1; pa.wfc2 = wfc2;
    prep_all_kernel<<<dim3(96, 8), 256, 0, stream>>>(pa);

    // ---- attention block ----
    ln_kernel<<<2048, 256, 0, stream>>>(xbuf, ln1_g + l * 1024, ln1_b + l * 1024, hbuf);
    gl<M_QKV>(stream, 2048, 3072, 1024, hbuf, 1024, wqkv, 1024, 0,
              nullptr, nullptr, nullptr, qbuf, kbuf, vbuf);      // 32x24 = 768 WGs
    attn_kernel<<<dim3(16, 32), 512, 0, stream>>>(qbuf, kbuf, vbuf, aout);
    // proj: split-K=4 (4x256), atomic combine into resid -> 1024 WGs
    gl<M_RESID>(stream, 2048, 1024, 256, aout, 1024, wproj, 1024, 0,
                nullptr, proj_b + l * 1024, xbuf,
                nullptr, nullptr, nullptr, 256, 256, 4);

    // ---- ffn block ----
    ln_kernel<<<2048, 256, 0, stream>>>(xbuf, ln2_g + l * 1024, ln2_b + l * 1024, hbuf);
    gl<M_FC1>(stream, 2048, 4096, 1024, hbuf, 1024, wfc1, 1024, 4096,
              abuf, fc1_b + l * 4096, nullptr);                  // 32x32 = 1024 WGs
    // fc2: split-K=4 (4x1024), atomic combine into resid -> 1024 WGs
    gl<M_RESID>(stream, 2048, 1024, 1024, abuf, 4096, wfc2, 4096, 0,
                nullptr, fc2_b + l * 1024, xbuf,
                nullptr, nullptr, nullptr, 1024, 1024, 4);
  }
}